// Round 10
// baseline (96.033 us; speedup 1.0000x reference)
//
#include <hip/hip_runtime.h>

#define NENT 100000
#define NREL 32
#define DIM  128
#define NB   2048

typedef short s8v __attribute__((ext_vector_type(8)));
typedef float f4v __attribute__((ext_vector_type(4)));

__device__ __forceinline__ unsigned short f2bf(float x){
  unsigned u = __float_as_uint(x);
  return (unsigned short)((u + 0x7fffu + ((u>>16)&1u)) >> 16);
}
__device__ __forceinline__ float bf2f(unsigned short u){
  return __uint_as_float(((unsigned)u) << 16);
}
__device__ __forceinline__ float lo2f(unsigned p){ return __uint_as_float(p << 16); }
__device__ __forceinline__ float hi2f(unsigned p){ return __uint_as_float(p & 0xffff0000u); }
__device__ __forceinline__ float leakyf(float x){ return x > 0.f ? x : 0.2f*x; }

#define SCALE_BLKS 25000

// ---------------- init: scale2 (blocks < SCALE_BLKS) ∪ prep (2×128-thr halves per block)
__global__ __launch_bounds__(256) void k_init(const float* __restrict__ ent,
                                              const float* __restrict__ rel,
                                              const float* __restrict__ A1,
                                              const float* __restrict__ A2,
                                              const float* __restrict__ Wxw,
                                              const float* __restrict__ W1w,
                                              const float* __restrict__ W2w,
                                              unsigned* __restrict__ entB,
                                              float* __restrict__ Pg,
                                              unsigned short* __restrict__ A1Lf,
                                              unsigned short* __restrict__ A2f,
                                              unsigned short* __restrict__ WxF,
                                              unsigned short* __restrict__ W1F,
                                              unsigned short* __restrict__ W2F){
  int t = threadIdx.x;
  if (blockIdx.x < SCALE_BLKS){
    int row = blockIdx.x*4 + (t>>6);
    if (row >= NENT) return;
    int l = t & 63;
    float2 v = *(const float2*)(ent + (size_t)row*128 + 2*l);
    float ss = v.x*v.x + v.y*v.y;
    for (int m=1;m<64;m<<=1) ss += __shfl_xor(ss, m);
    float sc = fminf(1.f, 1.f/(sqrtf(ss) + 1e-7f));
    entB[(size_t)row*64 + l] = (unsigned)f2bf(sc*v.x) | ((unsigned)f2bf(sc*v.y) << 16);
    return;
  }
  int half = t>>7, tt = t&127;
  int blk = (blockIdx.x - SCALE_BLKS)*2 + half;
  __shared__ float srn[2][128];
  __shared__ float red[2][2];
  if (blk < 32){
    int r = blk;
    float v = rel[r*128 + tt];
    float ss = v*v;
    for (int m=1;m<64;m<<=1) ss += __shfl_xor(ss, m);
    if ((tt&63)==0) red[half][tt>>6] = ss;
    __syncthreads();
    float nrm = sqrtf(red[half][0]+red[half][1]);
    float f = fminf(1.f, 1.f/(nrm + 1e-7f));
    srn[half][tt] = v*f;
    __syncthreads();
    const float4* ar = (const float4*)(A1 + tt*256 + 128);
    float acc = 0.f;
#pragma unroll
    for (int k4=0;k4<32;k4++){
      float4 a = ar[k4];
      acc += a.x*srn[half][k4*4] + a.y*srn[half][k4*4+1]
           + a.z*srn[half][k4*4+2] + a.w*srn[half][k4*4+3];
    }
    Pg[r*128 + tt] = acc;
  } else if (blk < 64){
    int bb = blk - 32;
    int fid = bb*64 + (tt>>1);
    int hf = tt&1;
    int lane = fid & 63, kc = (fid>>6)&3, dt = fid>>8;
    int d = dt*16 + (lane&15);
    int kb = kc*32 + ((lane>>4)&3)*8 + hf*4;
#pragma unroll
    for (int i=0;i<4;i++)
      A2f[fid*8 + hf*4 + i] = f2bf(A2[d*128 + kb + i]);
  } else if (blk < 96){
    int bb = blk - 64;
    int fid = bb*64 + (tt>>1);
    int hf = tt&1;
    int lane = fid & 63, kc = (fid>>6)&3, dt = fid>>8;
    int d = dt*16 + (lane&15);
    int kb = kc*32 + ((lane>>4)&3)*8 + hf*4;
#pragma unroll
    for (int i=0;i<4;i++)
      A1Lf[fid*8 + hf*4 + i] = f2bf(A1[d*256 + kb + i]);
  } else if (blk < 160){
    int fid = (blk-96)*128 + tt;
    int l = fid&63, kc = (fid>>6)&3, nt = (fid>>8)&15, iter = (fid>>12)&1;
    int n = nt*16 + (l&15);
    int k = kc*32 + ((l>>4)&3)*8;
    const float* src = Wxw + ((size_t)((iter*2 + (n>>7))*128 + (n&127)))*128 + k;
#pragma unroll
    for (int j=0;j<8;j++) WxF[(size_t)fid*8 + j] = f2bf(src[j]);
  } else if (blk < 224){
    int fid = (blk-160)*128 + tt;
    int l = fid&63, kc = (fid>>6)&7, nt = (fid>>9)&15;
    int n = nt*16 + (l&15);
    int k = kc*32 + ((l>>4)&3)*8;
#pragma unroll
    for (int j=0;j<8;j++) W1F[(size_t)fid*8 + j] = f2bf(W1w[(size_t)n*256 + k + j]);
  } else {
    int fid = (blk-224)*128 + tt;
    int l = fid&63, kc = (fid>>6)&7, nt = (fid>>9)&15;
    int n = nt*16 + (l&15);
    int k = kc*32 + ((l>>4)&3)*8;
#pragma unroll
    for (int j=0;j<8;j++) W2F[(size_t)fid*8 + j] = f2bf(W2w[(size_t)n*256 + k + j]);
  }
}

// ---------------- fused body: 2 b/block, 4 waves: gather + scores + softmax + weighted sums
__global__ __launch_bounds__(256) void k_body(const int* __restrict__ eidx,
                                              const int* __restrict__ adjE,
                                              const int* __restrict__ adjR,
                                              const unsigned* __restrict__ entB,
                                              const unsigned short* __restrict__ A1Lf,
                                              const float* __restrict__ Pg,
                                              const unsigned short* __restrict__ A2f,
                                              const float* __restrict__ A3,
                                              float* __restrict__ Hb, float* __restrict__ S1,
                                              float* __restrict__ SV,
                                              float* __restrict__ out){
  int blk = blockIdx.x;
  int t = threadIdx.x, l = t&63, w = t>>6;
  __shared__ int sE1[2][16];
  __shared__ int sR0[2][16];
  __shared__ int sE2[2][256];
  __shared__ int sR1[2][256];
  __shared__ __align__(16) unsigned sAN[16*64];
  __shared__ float sC[4][132];
  __shared__ float sSC[2][64];
  __shared__ float sW0[2][16];
  __shared__ float sW1[2][256];
  __shared__ float sPartD[4][128];

  // ---- A1: hop-1 indices
  int e1 = 0;
  if (w < 2){
    int b = blk*2 + w;
    int idx = eidx[b];
    if (l < 16){
      e1 = adjE[idx*16 + l];
      sE1[w][l] = e1;
      sR0[w][l] = adjR[idx*16 + l];
    }
    if (l == 63) sE1[w][0] = sE1[w][0];  // no-op
    // stash idx in lane via shfl later; simpler: recompute below
  }
  __syncthreads();

  // ---- A2: anchors (w0/w1) ; hop-2 indices (w2/w3)
  if (w < 2){
    int b = blk*2 + w;
    int idx = eidx[b];
    float sx = 0.f, sy = 0.f;
#pragma unroll
    for (int i=0;i<16;i++){
      int e = __shfl(e1, i);
      unsigned pk = entB[(size_t)e*64 + l];
      sx += lo2f(pk); sy += hi2f(pk);
    }
    unsigned hp = entB[(size_t)idx*64 + l];
    float2 hv = { lo2f(hp), hi2f(hp) };
    *(float2*)(Hb + (size_t)b*128 + 2*l) = hv;
    *(float2*)(out + (size_t)b*640 + 512 + 2*l) = hv;
    float2 sv = { sx, sy };
    *(float2*)(S1 + (size_t)b*128 + 2*l) = sv;
    unsigned sp = (unsigned)f2bf(sx) | ((unsigned)f2bf(sy) << 16);
    int rowh = w*2, rows = w*2+1;
    *(unsigned*)((char*)sAN + ((rowh*256 + l*4) ^ ((rowh&7)<<4))) = hp;
    *(unsigned*)((char*)sAN + ((rows*256 + l*4) ^ ((rows&7)<<4))) = sp;
  } else {
    int bl = w - 2;
    int esrc = sE1[bl][l>>2];
    int4 e2 = *(const int4*)(adjE + (size_t)esrc*16 + (l&3)*4);
    int4 r1 = *(const int4*)(adjR + (size_t)esrc*16 + (l&3)*4);
    *(int4*)&sE2[bl][l*4] = e2;
    *(int4*)&sR1[bl][l*4] = r1;
  }
  __syncthreads();

  int cl = l&15, kg = l>>4;
  // ---- B1: G1 c = A1L @ anchors
  {
    s8v bf[4];
#pragma unroll
    for (int kc=0;kc<4;kc++)
      bf[kc] = *(const s8v*)((const char*)sAN + ((cl*256 + (kc*32+kg*8)*2) ^ ((cl&7)<<4)));
#pragma unroll
    for (int dth=0; dth<2; dth++){
      int dt = w*2 + dth;
      f4v acc = {0.f,0.f,0.f,0.f};
#pragma unroll
      for (int kc=0;kc<4;kc++){
        s8v af = *(const s8v*)(A1Lf + ((size_t)((dt*4+kc)*64 + l))*8);
        acc = __builtin_amdgcn_mfma_f32_16x16x32_bf16(af, bf[kc], acc, 0, 0, 0);
      }
      if (cl < 4){
#pragma unroll
        for (int r=0;r<4;r++) sC[cl][dt*16 + kg*4 + r] = acc[r];
      }
    }
  }
  __syncthreads();

  // ---- B2: G2 scores
  {
    s8v bfr0[4], bfr1[4];
#pragma unroll
    for (int cc=0; cc<2; cc++){
      int ct = w*2 + cc;
      int ci = ct >> 1;
      int rr = (ct&1)*16 + cl;
      s8v* bfr = cc ? bfr1 : bfr0;
#pragma unroll
      for (int kc=0;kc<4;kc++){
        int k0 = kc*32 + kg*8;
        float4 pa = *(const float4*)(Pg + rr*128 + k0);
        float4 pb = *(const float4*)(Pg + rr*128 + k0 + 4);
        bfr[kc][0] = (short)f2bf(fmaxf(sC[ci][k0+0]+pa.x, 0.f));
        bfr[kc][1] = (short)f2bf(fmaxf(sC[ci][k0+1]+pa.y, 0.f));
        bfr[kc][2] = (short)f2bf(fmaxf(sC[ci][k0+2]+pa.z, 0.f));
        bfr[kc][3] = (short)f2bf(fmaxf(sC[ci][k0+3]+pa.w, 0.f));
        bfr[kc][4] = (short)f2bf(fmaxf(sC[ci][k0+4]+pb.x, 0.f));
        bfr[kc][5] = (short)f2bf(fmaxf(sC[ci][k0+5]+pb.y, 0.f));
        bfr[kc][6] = (short)f2bf(fmaxf(sC[ci][k0+6]+pb.z, 0.f));
        bfr[kc][7] = (short)f2bf(fmaxf(sC[ci][k0+7]+pb.w, 0.f));
      }
    }
    float sacc0 = 0.f, sacc1 = 0.f;
#pragma unroll
    for (int dt=0; dt<8; dt++){
      f4v a40 = {0.f,0.f,0.f,0.f};
      f4v a41 = {0.f,0.f,0.f,0.f};
#pragma unroll
      for (int kc=0;kc<4;kc++){
        s8v af = *(const s8v*)(A2f + ((size_t)((dt*4+kc)*64 + l))*8);
        a40 = __builtin_amdgcn_mfma_f32_16x16x32_bf16(af, bfr0[kc], a40, 0, 0, 0);
        a41 = __builtin_amdgcn_mfma_f32_16x16x32_bf16(af, bfr1[kc], a41, 0, 0, 0);
      }
      float4 a3v = *(const float4*)(A3 + dt*16 + kg*4);
      sacc0 += fmaxf(a40[0],0.f)*a3v.x + fmaxf(a40[1],0.f)*a3v.y
             + fmaxf(a40[2],0.f)*a3v.z + fmaxf(a40[3],0.f)*a3v.w;
      sacc1 += fmaxf(a41[0],0.f)*a3v.x + fmaxf(a41[1],0.f)*a3v.y
             + fmaxf(a41[2],0.f)*a3v.z + fmaxf(a41[3],0.f)*a3v.w;
    }
    sacc0 += __shfl_xor(sacc0, 16); sacc0 += __shfl_xor(sacc0, 32);
    sacc1 += __shfl_xor(sacc1, 16); sacc1 += __shfl_xor(sacc1, 32);
    if (l < 16){
      int c0 = (w*2+0)*16 + l;
      int c1 = (w*2+1)*16 + l;
      sSC[c0>>6][c0&63] = 1.f/(1.f + __expf(-sacc0));
      sSC[c1>>6][c1&63] = 1.f/(1.f + __expf(-sacc1));
    }
  }
  __syncthreads();

  // ---- C: softmax weights
  if (w < 2){
    int4 ra = *(const int4*)&sR1[w][l*4];
    float e0 = __expf(sSC[w][32 + ra.x]);
    float e1_ = __expf(sSC[w][32 + ra.y]);
    float e2 = __expf(sSC[w][32 + ra.z]);
    float e3 = __expf(sSC[w][32 + ra.w]);
    float s = e0+e1_+e2+e3;
    for (int m=1;m<64;m<<=1) s += __shfl_xor(s, m);
    float inv = 1.f/s;
    sW1[w][l*4+0] = e0*inv;
    sW1[w][l*4+1] = e1_*inv;
    sW1[w][l*4+2] = e2*inv;
    sW1[w][l*4+3] = e3*inv;
    if (l < 16){
      float ee = __expf(sSC[w][sR0[w][l]]);
      float s0 = ee;
      for (int m=1;m<16;m<<=1) s0 += __shfl_xor(s0, m);
      sW0[w][l] = ee/s0;
    }
  }
  __syncthreads();

  // ---- D: weighted gathers -> SV
  {
    int bl = w>>1, half = w&1;
    int b = blk*2 + bl;
    float2 acc = {0.f, 0.f};
    if (half == 0){
#pragma unroll
      for (int i=0;i<16;i++){
        int e = sE1[bl][i];
        float f = sW0[bl][i];
        unsigned pk = entB[(size_t)e*64 + l];
        acc.x += f*lo2f(pk); acc.y += f*hi2f(pk);
      }
      *(float2*)(SV + ((size_t)b*2 + 0)*128 + 2*l) = acc;
      acc.x = 0.f; acc.y = 0.f;
    }
#pragma unroll 4
    for (int i=0;i<128;i++){
      int row = half*128 + i;
      int e = sE2[bl][row];
      float f = sW1[bl][row];
      unsigned pk = entB[(size_t)e*64 + l];
      acc.x += f*lo2f(pk); acc.y += f*hi2f(pk);
    }
    *(float2*)&sPartD[w][2*l] = acc;
  }
  __syncthreads();
  {
    int bl = t>>7, d = t&127;
    SV[((size_t)(blk*2+bl)*2 + 1)*128 + d] = sPartD[bl*2][d] + sPartD[bl*2+1][d];
  }
}

// ---------------- MFMA vagg (unchanged)
__global__ __launch_bounds__(256) void k_vagg2(const float* __restrict__ SV,
                                               const float* __restrict__ Hb,
                                               const float* __restrict__ S1,
                                               const unsigned short* __restrict__ WxF,
                                               const float* __restrict__ Wxb,
                                               const unsigned short* __restrict__ W1F,
                                               const float* __restrict__ W1b,
                                               const unsigned short* __restrict__ W2F,
                                               const float* __restrict__ W2b,
                                               float* __restrict__ out){
  int b0 = blockIdx.x * 32;
  int iter = blockIdx.y;
  int t = threadIdx.x, l = t&63, w = t>>6;
  int wm = w>>1, wn = w&1;
  __shared__ __align__(16) unsigned short sSV[32*128];
  __shared__ __align__(16) unsigned short sA [32*128];
  __shared__ __align__(16) unsigned short sV [32*256];
  char* sSVb = (char*)sSV; char* sAb = (char*)sA; char* sVb = (char*)sV;

  const float* anc = iter ? S1 : Hb;
  {
    int row = t>>3, c0 = (t&7)*16;
    const float* ps = SV + ((size_t)(b0+row)*2 + iter)*128 + c0;
    const float* pa = anc + (size_t)(b0+row)*128 + c0;
    int xo = (row&7)<<4;
#pragma unroll
    for (int c2=0;c2<8;c2++){
      float2 sv2 = *(const float2*)(ps + c2*2);
      float2 an2 = *(const float2*)(pa + c2*2);
      unsigned pv  = (unsigned)f2bf(sv2.x) | ((unsigned)f2bf(sv2.y)<<16);
      unsigned pan = (unsigned)f2bf(an2.x) | ((unsigned)f2bf(an2.y)<<16);
      int byte = (row*256 + c0*2 + c2*4) ^ xo;
      *(unsigned*)(sSVb + byte) = pv;
      *(unsigned*)(sAb  + byte) = pan;
    }
  }
  __syncthreads();

  int kl = l&15, kg = l>>4;
  {
    int rowg = wm*16 + kl;
    int xo = (rowg&7)<<4;
    s8v af[4];
#pragma unroll
    for (int kc=0;kc<4;kc++)
      af[kc] = *(const s8v*)(sSVb + ((rowg*256 + kc*64 + kg*16) ^ xo));
#pragma unroll
    for (int nt8=0;nt8<8;nt8++){
      int ntg = wn*8 + nt8;
      int n = ntg*16 + kl;
      float bias = Wxb[iter*256 + n];
      f4v acc = {bias,bias,bias,bias};
#pragma unroll
      for (int kc=0;kc<4;kc++){
        s8v bf = *(const s8v*)(WxF + ((size_t)(((iter*16 + ntg)*4 + kc)*64 + l))*8);
        acc = __builtin_amdgcn_mfma_f32_16x16x32_bf16(af[kc], bf, acc, 0, 0, 0);
      }
#pragma unroll
      for (int r=0;r<4;r++){
        int rowl = wm*16 + kg*4 + r;
        int byte = (rowl*512 + n*2) ^ ((rowl&7)<<4);
        *(unsigned short*)(sVb + byte) = f2bf(leakyf(acc[r]));
      }
    }
  }
  __syncthreads();
  {
    int rowl = wm*16 + kl;
    int xo = (rowl&7)<<4;
    s8v x1f[8], x2f[8];
#pragma unroll
    for (int kc=0;kc<8;kc++){
      int k0 = kc*32 + kg*8;
      s8v vv = *(const s8v*)(sVb + ((rowl*512 + k0*2) ^ xo));
      s8v aa = *(const s8v*)(sAb + ((rowl*256 + (k0&127)*2) ^ xo));
#pragma unroll
      for (int j=0;j<8;j++){
        float vf = bf2f((unsigned short)vv[j]);
        float av = bf2f((unsigned short)aa[j]);
        x1f[kc][j] = (short)f2bf(av + vf);
        x2f[kc][j] = (short)f2bf(av * vf);
      }
    }
    int obase = iter ? 0 : 256;
#pragma unroll
    for (int nt8=0;nt8<8;nt8++){
      int ntg = wn*8 + nt8;
      int n = ntg*16 + kl;
      float bb1 = W1b[n], bb2 = W2b[n];
      f4v a1 = {bb1,bb1,bb1,bb1};
      f4v a2 = {bb2,bb2,bb2,bb2};
#pragma unroll
      for (int kc=0;kc<8;kc++){
        s8v wf1 = *(const s8v*)(W1F + ((size_t)((ntg*8 + kc)*64 + l))*8);
        a1 = __builtin_amdgcn_mfma_f32_16x16x32_bf16(x1f[kc], wf1, a1, 0, 0, 0);
      }
#pragma unroll
      for (int kc=0;kc<8;kc++){
        s8v wf2 = *(const s8v*)(W2F + ((size_t)((ntg*8 + kc)*64 + l))*8);
        a2 = __builtin_amdgcn_mfma_f32_16x16x32_bf16(x2f[kc], wf2, a2, 0, 0, 0);
      }
#pragma unroll
      for (int r=0;r<4;r++){
        int row = wm*16 + kg*4 + r;
        out[(size_t)(b0+row)*640 + obase + n] = leakyf(a1[r]) + leakyf(a2[r]);
      }
    }
  }
}

extern "C" void kernel_launch(void* const* d_in, const int* in_sizes, int n_in,
                              void* d_out, int out_size, void* d_ws, size_t ws_size,
                              hipStream_t stream) {
  const int*   eidx = (const int*)d_in[0];
  const int*   adjE = (const int*)d_in[1];
  const int*   adjR = (const int*)d_in[2];
  const float* ent  = (const float*)d_in[3];
  const float* rel  = (const float*)d_in[4];
  const float* A1   = (const float*)d_in[5];
  const float* A2   = (const float*)d_in[6];
  const float* A3   = (const float*)d_in[7];
  const float* Wxw  = (const float*)d_in[8];
  const float* Wxb  = (const float*)d_in[9];
  const float* W1w  = (const float*)d_in[10];
  const float* W1b  = (const float*)d_in[11];
  const float* W2w  = (const float*)d_in[12];
  const float* W2b  = (const float*)d_in[13];
  float* out = (float*)d_out;

  char* wsb = (char*)d_ws;
  size_t off = 0;
  auto alloc = [&](size_t bytes)->char*{
    char* p = wsb + off; off += (bytes + 255) & ~(size_t)255; return p;
  };
  float* Pg   = (float*)alloc(NREL*DIM*4);
  unsigned short* A1Lf = (unsigned short*)alloc(2048*8*2);
  unsigned short* A2f  = (unsigned short*)alloc(2048*8*2);
  unsigned short* WxF = (unsigned short*)alloc((size_t)8192*8*2);
  unsigned short* W1F = (unsigned short*)alloc((size_t)8192*8*2);
  unsigned short* W2F = (unsigned short*)alloc((size_t)8192*8*2);
  unsigned* entB = (unsigned*)alloc((size_t)NENT*64*4);
  float* Hb = (float*)alloc((size_t)NB*DIM*4);
  float* S1 = (float*)alloc((size_t)NB*DIM*4);
  float* SV = (float*)alloc((size_t)NB*2*DIM*4);

  k_init<<<dim3(SCALE_BLKS + 144), dim3(256), 0, stream>>>(
      ent, rel, A1, A2, Wxw, W1w, W2w,
      entB, Pg, A1Lf, A2f, WxF, W1F, W2F);
  k_body<<<dim3(NB/2), dim3(256), 0, stream>>>(
      eidx, adjE, adjR, entB, A1Lf, Pg, A2f, A3, Hb, S1, SV, out);
  k_vagg2<<<dim3(NB/32, 2), dim3(256), 0, stream>>>(
      SV, Hb, S1, WxF, Wxb, W1F, W1b, W2F, W2b, out);
}

// Round 11
// 81.588 us; speedup vs baseline: 1.1770x; 1.1770x over previous
//
#include <hip/hip_runtime.h>

#define NENT 100000
#define NREL 32
#define DIM  128
#define NB   2048

typedef short s8v __attribute__((ext_vector_type(8)));
typedef float f4v __attribute__((ext_vector_type(4)));

__device__ __forceinline__ unsigned short f2bf(float x){
  unsigned u = __float_as_uint(x);
  return (unsigned short)((u + 0x7fffu + ((u>>16)&1u)) >> 16);
}
__device__ __forceinline__ float bf2f(unsigned short u){
  return __uint_as_float(((unsigned)u) << 16);
}
__device__ __forceinline__ float lo2f(unsigned p){ return __uint_as_float(p << 16); }
__device__ __forceinline__ float hi2f(unsigned p){ return __uint_as_float(p & 0xffff0000u); }
__device__ __forceinline__ float leakyf(float x){ return x > 0.f ? x : 0.2f*x; }

#define SCALE_BLKS 25000

// ---------------- init: scale2 (blocks < SCALE_BLKS) ∪ prep (2×128-thr halves per block)
__global__ __launch_bounds__(256) void k_init(const float* __restrict__ ent,
                                              const float* __restrict__ rel,
                                              const float* __restrict__ A1,
                                              const float* __restrict__ A2,
                                              const float* __restrict__ Wxw,
                                              const float* __restrict__ W1w,
                                              const float* __restrict__ W2w,
                                              unsigned* __restrict__ entB,
                                              float* __restrict__ Pg,
                                              unsigned short* __restrict__ A1Lf,
                                              unsigned short* __restrict__ A2f,
                                              unsigned short* __restrict__ WxF,
                                              unsigned short* __restrict__ W1F,
                                              unsigned short* __restrict__ W2F){
  int t = threadIdx.x;
  if (blockIdx.x < SCALE_BLKS){
    int row = blockIdx.x*4 + (t>>6);
    if (row >= NENT) return;
    int l = t & 63;
    float2 v = *(const float2*)(ent + (size_t)row*128 + 2*l);
    float ss = v.x*v.x + v.y*v.y;
    for (int m=1;m<64;m<<=1) ss += __shfl_xor(ss, m);
    float sc = fminf(1.f, 1.f/(sqrtf(ss) + 1e-7f));
    entB[(size_t)row*64 + l] = (unsigned)f2bf(sc*v.x) | ((unsigned)f2bf(sc*v.y) << 16);
    return;
  }
  int half = t>>7, tt = t&127;
  int blk = (blockIdx.x - SCALE_BLKS)*2 + half;
  __shared__ float srn[2][128];
  __shared__ float red[2][2];
  if (blk < 32){
    int r = blk;
    float v = rel[r*128 + tt];
    float ss = v*v;
    for (int m=1;m<64;m<<=1) ss += __shfl_xor(ss, m);
    if ((tt&63)==0) red[half][tt>>6] = ss;
    __syncthreads();
    float nrm = sqrtf(red[half][0]+red[half][1]);
    float f = fminf(1.f, 1.f/(nrm + 1e-7f));
    srn[half][tt] = v*f;
    __syncthreads();
    const float4* ar = (const float4*)(A1 + tt*256 + 128);
    float acc = 0.f;
#pragma unroll
    for (int k4=0;k4<32;k4++){
      float4 a = ar[k4];
      acc += a.x*srn[half][k4*4] + a.y*srn[half][k4*4+1]
           + a.z*srn[half][k4*4+2] + a.w*srn[half][k4*4+3];
    }
    Pg[r*128 + tt] = acc;
  } else if (blk < 64){
    int bb = blk - 32;
    int fid = bb*64 + (tt>>1);
    int hf = tt&1;
    int lane = fid & 63, kc = (fid>>6)&3, dt = fid>>8;
    int d = dt*16 + (lane&15);
    int kb = kc*32 + ((lane>>4)&3)*8 + hf*4;
#pragma unroll
    for (int i=0;i<4;i++)
      A2f[fid*8 + hf*4 + i] = f2bf(A2[d*128 + kb + i]);
  } else if (blk < 96){
    int bb = blk - 64;
    int fid = bb*64 + (tt>>1);
    int hf = tt&1;
    int lane = fid & 63, kc = (fid>>6)&3, dt = fid>>8;
    int d = dt*16 + (lane&15);
    int kb = kc*32 + ((lane>>4)&3)*8 + hf*4;
#pragma unroll
    for (int i=0;i<4;i++)
      A1Lf[fid*8 + hf*4 + i] = f2bf(A1[d*256 + kb + i]);
  } else if (blk < 160){
    int fid = (blk-96)*128 + tt;
    int l = fid&63, kc = (fid>>6)&3, nt = (fid>>8)&15, iter = (fid>>12)&1;
    int n = nt*16 + (l&15);
    int k = kc*32 + ((l>>4)&3)*8;
    const float* src = Wxw + ((size_t)((iter*2 + (n>>7))*128 + (n&127)))*128 + k;
#pragma unroll
    for (int j=0;j<8;j++) WxF[(size_t)fid*8 + j] = f2bf(src[j]);
  } else if (blk < 224){
    int fid = (blk-160)*128 + tt;
    int l = fid&63, kc = (fid>>6)&7, nt = (fid>>9)&15;
    int n = nt*16 + (l&15);
    int k = kc*32 + ((l>>4)&3)*8;
#pragma unroll
    for (int j=0;j<8;j++) W1F[(size_t)fid*8 + j] = f2bf(W1w[(size_t)n*256 + k + j]);
  } else {
    int fid = (blk-224)*128 + tt;
    int l = fid&63, kc = (fid>>6)&7, nt = (fid>>9)&15;
    int n = nt*16 + (l&15);
    int k = kc*32 + ((l>>4)&3)*8;
#pragma unroll
    for (int j=0;j<8;j++) W2F[(size_t)fid*8 + j] = f2bf(W2w[(size_t)n*256 + k + j]);
  }
}

// ---------------- 1 wave per b, barrier-free: indices + h + s1 + anchors
__global__ __launch_bounds__(64) void k_gath(const int* __restrict__ eidx,
                                             const int* __restrict__ adjE,
                                             const int* __restrict__ adjR,
                                             const unsigned* __restrict__ entB,
                                             int* __restrict__ E1g, int* __restrict__ E2g,
                                             int* __restrict__ R0g, int* __restrict__ R1g,
                                             unsigned* __restrict__ ANb,
                                             float* __restrict__ Hb, float* __restrict__ S1,
                                             float* __restrict__ out){
  int b = blockIdx.x, l = threadIdx.x;
  int idx = eidx[b];
  int e1 = 0;
  if (l < 16){
    e1 = adjE[idx*16 + l];
    E1g[b*16+l] = e1;
    R0g[b*16+l] = adjR[idx*16 + l];
  }
  int esrc = __shfl(e1, l>>2);
  int4 e2 = *(const int4*)(adjE + (size_t)esrc*16 + (l&3)*4);
  int4 r1 = *(const int4*)(adjR + (size_t)esrc*16 + (l&3)*4);
  *(int4*)(E2g + (size_t)b*256 + l*4) = e2;
  *(int4*)(R1g + (size_t)b*256 + l*4) = r1;
  float sx = 0.f, sy = 0.f;
#pragma unroll
  for (int i=0;i<16;i++){
    int e = __shfl(e1, i);
    unsigned pk = entB[(size_t)e*64 + l];
    sx += lo2f(pk); sy += hi2f(pk);
  }
  unsigned hp = entB[(size_t)idx*64 + l];
  ANb[((size_t)b*2 + 0)*64 + l] = hp;
  float2 hv = { lo2f(hp), hi2f(hp) };
  *(float2*)(Hb + b*128 + 2*l) = hv;
  *(float2*)(out + (size_t)b*640 + 512 + 2*l) = hv;
  ANb[((size_t)b*2 + 1)*64 + l] = (unsigned)f2bf(sx) | ((unsigned)f2bf(sy) << 16);
  float2 sv = { sx, sy };
  *(float2*)(S1 + b*128 + 2*l) = sv;
}

// ---------------- batched scores: 2 b/block, A2f LDS-staged, loop-inverted
__global__ __launch_bounds__(256) void k_score2(const unsigned* __restrict__ ANb,
                                                const unsigned short* __restrict__ A1Lf,
                                                const float* __restrict__ Pg,
                                                const unsigned short* __restrict__ A2f,
                                                const float* __restrict__ A3,
                                                const int* __restrict__ R0g,
                                                const int* __restrict__ R1g,
                                                float* __restrict__ W0g,
                                                float* __restrict__ W1g){
  int blk = blockIdx.x;              // 2 b per block
  int t = threadIdx.x, l = t&63, w = t>>6;
  __shared__ __align__(16) unsigned short sA2f[2048*8];  // 32 KB, linear frag copy
  __shared__ __align__(16) unsigned sAN[16*64];          // anchors bf16x2, xor-swizzled (rows 4..15 zero)
  __shared__ float sC[4][132];                           // c[anchor][d]
  __shared__ float sSC[2][64];                           // scores per b

  { // stage A2f (32 KB) + anchors
    const uint4* src = (const uint4*)A2f;
    uint4* dst = (uint4*)sA2f;
#pragma unroll
    for (int i=0;i<8;i++) dst[t + i*256] = src[t + i*256];
    int row = t>>4, seg = t&15;
    uint4 v = {0u,0u,0u,0u};
    if (t < 64) v = *(const uint4*)(ANb + ((size_t)blk*4 + row)*64 + seg*4);
    *(uint4*)((char*)sAN + ((row*256 + seg*16) ^ ((row&7)<<4))) = v;
  }
  __syncthreads();

  int cl = l&15, kg = l>>4;
  { // G1: c = A1L @ AN ; wave w -> dt = w*2, w*2+1
    s8v bf[4];
#pragma unroll
    for (int kc=0;kc<4;kc++)
      bf[kc] = *(const s8v*)((const char*)sAN + ((cl*256 + (kc*32+kg*8)*2) ^ ((cl&7)<<4)));
#pragma unroll
    for (int dth=0; dth<2; dth++){
      int dt = w*2 + dth;
      f4v acc = {0.f,0.f,0.f,0.f};
#pragma unroll
      for (int kc=0;kc<4;kc++){
        s8v af = *(const s8v*)(A1Lf + ((size_t)((dt*4+kc)*64 + l))*8);
        acc = __builtin_amdgcn_mfma_f32_16x16x32_bf16(af, bf[kc], acc, 0, 0, 0);
      }
      if (cl < 4){
#pragma unroll
        for (int r=0;r<4;r++) sC[cl][dt*16 + kg*4 + r] = acc[r];
      }
    }
  }
  __syncthreads();

  { // G2: wave w handles ct = w*2 + {0,1}; A2f from LDS, loaded once, reused across cc
    s8v bfr0[4], bfr1[4];
#pragma unroll
    for (int cc=0; cc<2; cc++){
      int ct = w*2 + cc;
      int ci = ct >> 1;
      int rr = (ct&1)*16 + cl;
      s8v* bfr = cc ? bfr1 : bfr0;
#pragma unroll
      for (int kc=0;kc<4;kc++){
        int k0 = kc*32 + kg*8;
        float4 pa = *(const float4*)(Pg + rr*128 + k0);
        float4 pb = *(const float4*)(Pg + rr*128 + k0 + 4);
        bfr[kc][0] = (short)f2bf(fmaxf(sC[ci][k0+0]+pa.x, 0.f));
        bfr[kc][1] = (short)f2bf(fmaxf(sC[ci][k0+1]+pa.y, 0.f));
        bfr[kc][2] = (short)f2bf(fmaxf(sC[ci][k0+2]+pa.z, 0.f));
        bfr[kc][3] = (short)f2bf(fmaxf(sC[ci][k0+3]+pa.w, 0.f));
        bfr[kc][4] = (short)f2bf(fmaxf(sC[ci][k0+4]+pb.x, 0.f));
        bfr[kc][5] = (short)f2bf(fmaxf(sC[ci][k0+5]+pb.y, 0.f));
        bfr[kc][6] = (short)f2bf(fmaxf(sC[ci][k0+6]+pb.z, 0.f));
        bfr[kc][7] = (short)f2bf(fmaxf(sC[ci][k0+7]+pb.w, 0.f));
      }
    }
    float sacc0 = 0.f, sacc1 = 0.f;
#pragma unroll
    for (int dt=0; dt<8; dt++){
      f4v a40 = {0.f,0.f,0.f,0.f};
      f4v a41 = {0.f,0.f,0.f,0.f};
#pragma unroll
      for (int kc=0;kc<4;kc++){
        s8v af = *(const s8v*)(sA2f + ((dt*4+kc)*64 + l)*8);
        a40 = __builtin_amdgcn_mfma_f32_16x16x32_bf16(af, bfr0[kc], a40, 0, 0, 0);
        a41 = __builtin_amdgcn_mfma_f32_16x16x32_bf16(af, bfr1[kc], a41, 0, 0, 0);
      }
      float4 a3v = *(const float4*)(A3 + dt*16 + kg*4);
      sacc0 += fmaxf(a40[0],0.f)*a3v.x + fmaxf(a40[1],0.f)*a3v.y
             + fmaxf(a40[2],0.f)*a3v.z + fmaxf(a40[3],0.f)*a3v.w;
      sacc1 += fmaxf(a41[0],0.f)*a3v.x + fmaxf(a41[1],0.f)*a3v.y
             + fmaxf(a41[2],0.f)*a3v.z + fmaxf(a41[3],0.f)*a3v.w;
    }
    sacc0 += __shfl_xor(sacc0, 16); sacc0 += __shfl_xor(sacc0, 32);
    sacc1 += __shfl_xor(sacc1, 16); sacc1 += __shfl_xor(sacc1, 32);
    if (l < 16){
      int c0 = (w*2+0)*16 + l;
      int c1 = (w*2+1)*16 + l;
      sSC[c0>>6][c0&63] = 1.f/(1.f + __expf(-sacc0));
      sSC[c1>>6][c1&63] = 1.f/(1.f + __expf(-sacc1));
    }
  }
  __syncthreads();

  if (w < 2){ // softmax: wave w -> b = blk*2 + w
    int b = blk*2 + w;
    int4 ra = *(const int4*)(R1g + (size_t)b*256 + l*4);
    float e0 = __expf(sSC[w][32 + ra.x]);
    float e1 = __expf(sSC[w][32 + ra.y]);
    float e2 = __expf(sSC[w][32 + ra.z]);
    float e3 = __expf(sSC[w][32 + ra.w]);
    float s = e0+e1+e2+e3;
    for (int m=1;m<64;m<<=1) s += __shfl_xor(s, m);
    float inv = 1.f/s;
    float4 o = { e0*inv, e1*inv, e2*inv, e3*inv };
    *(float4*)(W1g + (size_t)b*256 + l*4) = o;
    if (l < 16){
      float ee = __expf(sSC[w][R0g[b*16 + l]]);
      float s0 = ee;
      for (int m=1;m<16;m<<=1) s0 += __shfl_xor(s0, m);
      W0g[b*16 + l] = ee/s0;
    }
  }
}

// ---------------- weighted gathers (bf16 entB, precomputed weights) -> SV
__global__ __launch_bounds__(256) void k_sv2(const int* __restrict__ E1g,
                                             const int* __restrict__ E2g,
                                             const float* __restrict__ W0g,
                                             const float* __restrict__ W1g,
                                             const unsigned* __restrict__ entB,
                                             float* __restrict__ SV){
  int b = blockIdx.x, t = threadIdx.x, l = t&63, w = t>>6;
  __shared__ float sW0[16];
  __shared__ float sW1[256];
  __shared__ int sE1[16];
  __shared__ int sE2[256];
  __shared__ float sPart[4][128];
  if (t < 16){ sE1[t] = E1g[b*16+t]; sW0[t] = W0g[b*16+t]; }
  sE2[t] = E2g[b*256+t];
  sW1[t] = W1g[b*256+t];
  __syncthreads();

  float2 a0 = {0.f,0.f};
#pragma unroll
  for (int i=0;i<4;i++){
    int row = w*4 + i;
    float f = sW0[row];
    unsigned pk = entB[(size_t)sE1[row]*64 + l];
    a0.x += f*lo2f(pk); a0.y += f*hi2f(pk);
  }
  float2 a1 = {0.f,0.f};
#pragma unroll 4
  for (int i=0;i<64;i++){
    int row = w*64 + i;
    float f = sW1[row];
    unsigned pk = entB[(size_t)sE2[row]*64 + l];
    a1.x += f*lo2f(pk); a1.y += f*hi2f(pk);
  }
  *(float2*)&sPart[w][2*l] = a0;
  __syncthreads();
  if (t < 128) SV[((size_t)b*2 + 0)*128 + t] = sPart[0][t]+sPart[1][t]+sPart[2][t]+sPart[3][t];
  __syncthreads();
  *(float2*)&sPart[w][2*l] = a1;
  __syncthreads();
  if (t < 128) SV[((size_t)b*2 + 1)*128 + t] = sPart[0][t]+sPart[1][t]+sPart[2][t]+sPart[3][t];
}

// ---------------- MFMA vagg: G1 V=leaky(Wx@sv+b) ; G2 e=leaky(W1@x1+b1)+leaky(W2@x2+b2)
__global__ __launch_bounds__(256) void k_vagg2(const float* __restrict__ SV,
                                               const float* __restrict__ Hb,
                                               const float* __restrict__ S1,
                                               const unsigned short* __restrict__ WxF,
                                               const float* __restrict__ Wxb,
                                               const unsigned short* __restrict__ W1F,
                                               const float* __restrict__ W1b,
                                               const unsigned short* __restrict__ W2F,
                                               const float* __restrict__ W2b,
                                               float* __restrict__ out){
  int b0 = blockIdx.x * 32;
  int iter = blockIdx.y;
  int t = threadIdx.x, l = t&63, w = t>>6;
  int wm = w>>1, wn = w&1;
  __shared__ __align__(16) unsigned short sSV[32*128];
  __shared__ __align__(16) unsigned short sA [32*128];
  __shared__ __align__(16) unsigned short sV [32*256];
  char* sSVb = (char*)sSV; char* sAb = (char*)sA; char* sVb = (char*)sV;

  const float* anc = iter ? S1 : Hb;
  {
    int row = t>>3, c0 = (t&7)*16;
    const float* ps = SV + ((size_t)(b0+row)*2 + iter)*128 + c0;
    const float* pa = anc + (size_t)(b0+row)*128 + c0;
    int xo = (row&7)<<4;
#pragma unroll
    for (int c2=0;c2<8;c2++){
      float2 sv2 = *(const float2*)(ps + c2*2);
      float2 an2 = *(const float2*)(pa + c2*2);
      unsigned pv  = (unsigned)f2bf(sv2.x) | ((unsigned)f2bf(sv2.y)<<16);
      unsigned pan = (unsigned)f2bf(an2.x) | ((unsigned)f2bf(an2.y)<<16);
      int byte = (row*256 + c0*2 + c2*4) ^ xo;
      *(unsigned*)(sSVb + byte) = pv;
      *(unsigned*)(sAb  + byte) = pan;
    }
  }
  __syncthreads();

  int kl = l&15, kg = l>>4;
  {
    int rowg = wm*16 + kl;
    int xo = (rowg&7)<<4;
    s8v af[4];
#pragma unroll
    for (int kc=0;kc<4;kc++)
      af[kc] = *(const s8v*)(sSVb + ((rowg*256 + kc*64 + kg*16) ^ xo));
#pragma unroll
    for (int nt8=0;nt8<8;nt8++){
      int ntg = wn*8 + nt8;
      int n = ntg*16 + kl;
      float bias = Wxb[iter*256 + n];
      f4v acc = {bias,bias,bias,bias};
#pragma unroll
      for (int kc=0;kc<4;kc++){
        s8v bf = *(const s8v*)(WxF + ((size_t)(((iter*16 + ntg)*4 + kc)*64 + l))*8);
        acc = __builtin_amdgcn_mfma_f32_16x16x32_bf16(af[kc], bf, acc, 0, 0, 0);
      }
#pragma unroll
      for (int r=0;r<4;r++){
        int rowl = wm*16 + kg*4 + r;
        int byte = (rowl*512 + n*2) ^ ((rowl&7)<<4);
        *(unsigned short*)(sVb + byte) = f2bf(leakyf(acc[r]));
      }
    }
  }
  __syncthreads();
  {
    int rowl = wm*16 + kl;
    int xo = (rowl&7)<<4;
    s8v x1f[8], x2f[8];
#pragma unroll
    for (int kc=0;kc<8;kc++){
      int k0 = kc*32 + kg*8;
      s8v vv = *(const s8v*)(sVb + ((rowl*512 + k0*2) ^ xo));
      s8v aa = *(const s8v*)(sAb + ((rowl*256 + (k0&127)*2) ^ xo));
#pragma unroll
      for (int j=0;j<8;j++){
        float vf = bf2f((unsigned short)vv[j]);
        float av = bf2f((unsigned short)aa[j]);
        x1f[kc][j] = (short)f2bf(av + vf);
        x2f[kc][j] = (short)f2bf(av * vf);
      }
    }
    int obase = iter ? 0 : 256;
#pragma unroll
    for (int nt8=0;nt8<8;nt8++){
      int ntg = wn*8 + nt8;
      int n = ntg*16 + kl;
      float bb1 = W1b[n], bb2 = W2b[n];
      f4v a1 = {bb1,bb1,bb1,bb1};
      f4v a2 = {bb2,bb2,bb2,bb2};
#pragma unroll
      for (int kc=0;kc<8;kc++){
        s8v wf1 = *(const s8v*)(W1F + ((size_t)((ntg*8 + kc)*64 + l))*8);
        a1 = __builtin_amdgcn_mfma_f32_16x16x32_bf16(x1f[kc], wf1, a1, 0, 0, 0);
      }
#pragma unroll
      for (int kc=0;kc<8;kc++){
        s8v wf2 = *(const s8v*)(W2F + ((size_t)((ntg*8 + kc)*64 + l))*8);
        a2 = __builtin_amdgcn_mfma_f32_16x16x32_bf16(x2f[kc], wf2, a2, 0, 0, 0);
      }
#pragma unroll
      for (int r=0;r<4;r++){
        int row = wm*16 + kg*4 + r;
        out[(size_t)(b0+row)*640 + obase + n] = leakyf(a1[r]) + leakyf(a2[r]);
      }
    }
  }
}

extern "C" void kernel_launch(void* const* d_in, const int* in_sizes, int n_in,
                              void* d_out, int out_size, void* d_ws, size_t ws_size,
                              hipStream_t stream) {
  const int*   eidx = (const int*)d_in[0];
  const int*   adjE = (const int*)d_in[1];
  const int*   adjR = (const int*)d_in[2];
  const float* ent  = (const float*)d_in[3];
  const float* rel  = (const float*)d_in[4];
  const float* A1   = (const float*)d_in[5];
  const float* A2   = (const float*)d_in[6];
  const float* A3   = (const float*)d_in[7];
  const float* Wxw  = (const float*)d_in[8];
  const float* Wxb  = (const float*)d_in[9];
  const float* W1w  = (const float*)d_in[10];
  const float* W1b  = (const float*)d_in[11];
  const float* W2w  = (const float*)d_in[12];
  const float* W2b  = (const float*)d_in[13];
  float* out = (float*)d_out;

  char* wsb = (char*)d_ws;
  size_t off = 0;
  auto alloc = [&](size_t bytes)->char*{
    char* p = wsb + off; off += (bytes + 255) & ~(size_t)255; return p;
  };
  float* Pg   = (float*)alloc(NREL*DIM*4);
  unsigned short* A1Lf = (unsigned short*)alloc(2048*8*2);
  unsigned short* A2f  = (unsigned short*)alloc(2048*8*2);
  unsigned short* WxF = (unsigned short*)alloc((size_t)8192*8*2);
  unsigned short* W1F = (unsigned short*)alloc((size_t)8192*8*2);
  unsigned short* W2F = (unsigned short*)alloc((size_t)8192*8*2);
  unsigned* entB = (unsigned*)alloc((size_t)NENT*64*4);
  unsigned* ANb  = (unsigned*)alloc((size_t)NB*2*64*4);
  float* Hb = (float*)alloc((size_t)NB*DIM*4);
  float* S1 = (float*)alloc((size_t)NB*DIM*4);
  float* SV = (float*)alloc((size_t)NB*2*DIM*4);
  int* E1g = (int*)alloc((size_t)NB*16*4);
  int* E2g = (int*)alloc((size_t)NB*256*4);
  int* R0g = (int*)alloc((size_t)NB*16*4);
  int* R1g = (int*)alloc((size_t)NB*256*4);
  float* W0g = (float*)alloc((size_t)NB*16*4);
  float* W1g = (float*)alloc((size_t)NB*256*4);

  k_init<<<dim3(SCALE_BLKS + 144), dim3(256), 0, stream>>>(
      ent, rel, A1, A2, Wxw, W1w, W2w,
      entB, Pg, A1Lf, A2f, WxF, W1F, W2F);
  k_gath<<<dim3(NB),     dim3(64), 0, stream>>>(eidx, adjE, adjR, entB,
                                                E1g, E2g, R0g, R1g, ANb, Hb, S1, out);
  k_score2<<<dim3(NB/2), dim3(256), 0, stream>>>(ANb, A1Lf, Pg, A2f, A3,
                                                 R0g, R1g, W0g, W1g);
  k_sv2 <<<dim3(NB),     dim3(256), 0, stream>>>(E1g, E2g, W0g, W1g, entB, SV);
  k_vagg2<<<dim3(NB/32, 2), dim3(256), 0, stream>>>(SV, Hb, S1, WxF, Wxb,
                                                    W1F, W1b, W2F, W2b, out);
}

// Round 12
// 75.213 us; speedup vs baseline: 1.2768x; 1.0848x over previous
//
#include <hip/hip_runtime.h>

#define NENT 100000
#define NREL 32
#define DIM  128
#define NB   2048

typedef short s8v __attribute__((ext_vector_type(8)));
typedef float f4v __attribute__((ext_vector_type(4)));

__device__ __forceinline__ unsigned short f2bf(float x){
  unsigned u = __float_as_uint(x);
  return (unsigned short)((u + 0x7fffu + ((u>>16)&1u)) >> 16);
}
__device__ __forceinline__ float bf2f(unsigned short u){
  return __uint_as_float(((unsigned)u) << 16);
}
__device__ __forceinline__ float lo2f(unsigned p){ return __uint_as_float(p << 16); }
__device__ __forceinline__ float hi2f(unsigned p){ return __uint_as_float(p & 0xffff0000u); }
__device__ __forceinline__ float leakyf(float x){ return x > 0.f ? x : 0.2f*x; }

#define SCALE_BLKS 25000

// ---------------- init: scale (entB bf16 + entF fp8) ∪ prep (2×128-thr halves per block)
__global__ __launch_bounds__(256) void k_init(const float* __restrict__ ent,
                                              const float* __restrict__ rel,
                                              const float* __restrict__ A1,
                                              const float* __restrict__ A2,
                                              const float* __restrict__ Wxw,
                                              const float* __restrict__ W1w,
                                              const float* __restrict__ W2w,
                                              unsigned* __restrict__ entB,
                                              unsigned short* __restrict__ entF,
                                              float* __restrict__ Pg,
                                              unsigned short* __restrict__ A1Lf,
                                              unsigned short* __restrict__ A2f,
                                              unsigned short* __restrict__ WxF,
                                              unsigned short* __restrict__ W1F,
                                              unsigned short* __restrict__ W2F){
  int t = threadIdx.x;
  if (blockIdx.x < SCALE_BLKS){
    int row = blockIdx.x*4 + (t>>6);
    if (row >= NENT) return;
    int l = t & 63;
    float2 v = *(const float2*)(ent + (size_t)row*128 + 2*l);
    float ss = v.x*v.x + v.y*v.y;
    for (int m=1;m<64;m<<=1) ss += __shfl_xor(ss, m);
    float sc = fminf(1.f, 1.f/(sqrtf(ss) + 1e-7f));
    float x = sc*v.x, y = sc*v.y;
    entB[(size_t)row*64 + l] = (unsigned)f2bf(x) | ((unsigned)f2bf(y) << 16);
    int p8 = __builtin_amdgcn_cvt_pk_fp8_f32(x, y, 0, false);
    entF[(size_t)row*64 + l] = (unsigned short)p8;
    return;
  }
  int half = t>>7, tt = t&127;
  int blk = (blockIdx.x - SCALE_BLKS)*2 + half;
  __shared__ float srn[2][128];
  __shared__ float red[2][2];
  if (blk < 32){
    int r = blk;
    float v = rel[r*128 + tt];
    float ss = v*v;
    for (int m=1;m<64;m<<=1) ss += __shfl_xor(ss, m);
    if ((tt&63)==0) red[half][tt>>6] = ss;
    __syncthreads();
    float nrm = sqrtf(red[half][0]+red[half][1]);
    float f = fminf(1.f, 1.f/(nrm + 1e-7f));
    srn[half][tt] = v*f;
    __syncthreads();
    const float4* ar = (const float4*)(A1 + tt*256 + 128);
    float acc = 0.f;
#pragma unroll
    for (int k4=0;k4<32;k4++){
      float4 a = ar[k4];
      acc += a.x*srn[half][k4*4] + a.y*srn[half][k4*4+1]
           + a.z*srn[half][k4*4+2] + a.w*srn[half][k4*4+3];
    }
    Pg[r*128 + tt] = acc;
  } else if (blk < 64){
    int bb = blk - 32;
    int fid = bb*64 + (tt>>1);
    int hf = tt&1;
    int lane = fid & 63, kc = (fid>>6)&3, dt = fid>>8;
    int d = dt*16 + (lane&15);
    int kb = kc*32 + ((lane>>4)&3)*8 + hf*4;
#pragma unroll
    for (int i=0;i<4;i++)
      A2f[fid*8 + hf*4 + i] = f2bf(A2[d*128 + kb + i]);
  } else if (blk < 96){
    int bb = blk - 64;
    int fid = bb*64 + (tt>>1);
    int hf = tt&1;
    int lane = fid & 63, kc = (fid>>6)&3, dt = fid>>8;
    int d = dt*16 + (lane&15);
    int kb = kc*32 + ((lane>>4)&3)*8 + hf*4;
#pragma unroll
    for (int i=0;i<4;i++)
      A1Lf[fid*8 + hf*4 + i] = f2bf(A1[d*256 + kb + i]);
  } else if (blk < 160){
    int fid = (blk-96)*128 + tt;
    int l = fid&63, kc = (fid>>6)&3, nt = (fid>>8)&15, iter = (fid>>12)&1;
    int n = nt*16 + (l&15);
    int k = kc*32 + ((l>>4)&3)*8;
    const float* src = Wxw + ((size_t)((iter*2 + (n>>7))*128 + (n&127)))*128 + k;
#pragma unroll
    for (int j=0;j<8;j++) WxF[(size_t)fid*8 + j] = f2bf(src[j]);
  } else if (blk < 224){
    int fid = (blk-160)*128 + tt;
    int l = fid&63, kc = (fid>>6)&7, nt = (fid>>9)&15;
    int n = nt*16 + (l&15);
    int k = kc*32 + ((l>>4)&3)*8;
#pragma unroll
    for (int j=0;j<8;j++) W1F[(size_t)fid*8 + j] = f2bf(W1w[(size_t)n*256 + k + j]);
  } else {
    int fid = (blk-224)*128 + tt;
    int l = fid&63, kc = (fid>>6)&7, nt = (fid>>9)&15;
    int n = nt*16 + (l&15);
    int k = kc*32 + ((l>>4)&3)*8;
#pragma unroll
    for (int j=0;j<8;j++) W2F[(size_t)fid*8 + j] = f2bf(W2w[(size_t)n*256 + k + j]);
  }
}

// ---------------- 1 wave per b, barrier-free: indices + h + s1 + anchors
__global__ __launch_bounds__(64) void k_gath(const int* __restrict__ eidx,
                                             const int* __restrict__ adjE,
                                             const int* __restrict__ adjR,
                                             const unsigned* __restrict__ entB,
                                             int* __restrict__ E1g, int* __restrict__ E2g,
                                             int* __restrict__ R0g, int* __restrict__ R1g,
                                             unsigned* __restrict__ ANb,
                                             float* __restrict__ Hb, float* __restrict__ S1,
                                             float* __restrict__ out){
  int b = blockIdx.x, l = threadIdx.x;
  int idx = eidx[b];
  int e1 = 0;
  if (l < 16){
    e1 = adjE[idx*16 + l];
    E1g[b*16+l] = e1;
    R0g[b*16+l] = adjR[idx*16 + l];
  }
  int esrc = __shfl(e1, l>>2);
  int4 e2 = *(const int4*)(adjE + (size_t)esrc*16 + (l&3)*4);
  int4 r1 = *(const int4*)(adjR + (size_t)esrc*16 + (l&3)*4);
  *(int4*)(E2g + (size_t)b*256 + l*4) = e2;
  *(int4*)(R1g + (size_t)b*256 + l*4) = r1;
  float sx = 0.f, sy = 0.f;
#pragma unroll
  for (int i=0;i<16;i++){
    int e = __shfl(e1, i);
    unsigned pk = entB[(size_t)e*64 + l];
    sx += lo2f(pk); sy += hi2f(pk);
  }
  unsigned hp = entB[(size_t)idx*64 + l];
  ANb[((size_t)b*2 + 0)*64 + l] = hp;
  float2 hv = { lo2f(hp), hi2f(hp) };
  *(float2*)(Hb + b*128 + 2*l) = hv;
  *(float2*)(out + (size_t)b*640 + 512 + 2*l) = hv;
  ANb[((size_t)b*2 + 1)*64 + l] = (unsigned)f2bf(sx) | ((unsigned)f2bf(sy) << 16);
  float2 sv = { sx, sy };
  *(float2*)(S1 + b*128 + 2*l) = sv;
}

// ---------------- batched scores: 4 b/block, 8 waves, A2f LDS-staged
__global__ __launch_bounds__(512) void k_score2(const unsigned* __restrict__ ANb,
                                                const unsigned short* __restrict__ A1Lf,
                                                const float* __restrict__ Pg,
                                                const unsigned short* __restrict__ A2f,
                                                const float* __restrict__ A3,
                                                const int* __restrict__ R0g,
                                                const int* __restrict__ R1g,
                                                float* __restrict__ W0g,
                                                float* __restrict__ W1g){
  int blk = blockIdx.x;              // 4 b per block
  int t = threadIdx.x, l = t&63, w = t>>6;   // 8 waves
  __shared__ __align__(16) unsigned short sA2f[2048*8];  // 32 KB
  __shared__ __align__(16) unsigned sAN[16*64];          // 8 anchors (rows 8..15 zero), swizzled
  __shared__ float sC[8][132];
  __shared__ float sSC[4][64];

  { // stage A2f (32 KB, 4 uint4/thread) + anchors
    const uint4* src = (const uint4*)A2f;
    uint4* dst = (uint4*)sA2f;
#pragma unroll
    for (int i=0;i<4;i++) dst[t + i*512] = src[t + i*512];
    if (t < 256){
      int row = t>>4, seg = t&15;
      uint4 v = {0u,0u,0u,0u};
      if (row < 8) v = *(const uint4*)(ANb + ((size_t)blk*8 + row)*64 + seg*4);
      *(uint4*)((char*)sAN + ((row*256 + seg*16) ^ ((row&7)<<4))) = v;
    }
  }
  __syncthreads();

  int cl = l&15, kg = l>>4;
  { // G1: c = A1L @ anchors ; wave w -> dt = w
    s8v bf[4];
#pragma unroll
    for (int kc=0;kc<4;kc++)
      bf[kc] = *(const s8v*)((const char*)sAN + ((cl*256 + (kc*32+kg*8)*2) ^ ((cl&7)<<4)));
    int dt = w;
    f4v acc = {0.f,0.f,0.f,0.f};
#pragma unroll
    for (int kc=0;kc<4;kc++){
      s8v af = *(const s8v*)(A1Lf + ((size_t)((dt*4+kc)*64 + l))*8);
      acc = __builtin_amdgcn_mfma_f32_16x16x32_bf16(af, bf[kc], acc, 0, 0, 0);
    }
    if (cl < 8){
#pragma unroll
      for (int r=0;r<4;r++) sC[cl][dt*16 + kg*4 + r] = acc[r];
    }
  }
  __syncthreads();

  { // G2: wave w -> anchor ci = w ; cc splits relations (rr = cc*16+cl)
    s8v bfr0[4], bfr1[4];
#pragma unroll
    for (int cc=0; cc<2; cc++){
      int ci = w;
      int rr = cc*16 + cl;
      s8v* bfr = cc ? bfr1 : bfr0;
#pragma unroll
      for (int kc=0;kc<4;kc++){
        int k0 = kc*32 + kg*8;
        float4 pa = *(const float4*)(Pg + rr*128 + k0);
        float4 pb = *(const float4*)(Pg + rr*128 + k0 + 4);
        bfr[kc][0] = (short)f2bf(fmaxf(sC[ci][k0+0]+pa.x, 0.f));
        bfr[kc][1] = (short)f2bf(fmaxf(sC[ci][k0+1]+pa.y, 0.f));
        bfr[kc][2] = (short)f2bf(fmaxf(sC[ci][k0+2]+pa.z, 0.f));
        bfr[kc][3] = (short)f2bf(fmaxf(sC[ci][k0+3]+pa.w, 0.f));
        bfr[kc][4] = (short)f2bf(fmaxf(sC[ci][k0+4]+pb.x, 0.f));
        bfr[kc][5] = (short)f2bf(fmaxf(sC[ci][k0+5]+pb.y, 0.f));
        bfr[kc][6] = (short)f2bf(fmaxf(sC[ci][k0+6]+pb.z, 0.f));
        bfr[kc][7] = (short)f2bf(fmaxf(sC[ci][k0+7]+pb.w, 0.f));
      }
    }
    float sacc0 = 0.f, sacc1 = 0.f;
#pragma unroll
    for (int dt=0; dt<8; dt++){
      f4v a40 = {0.f,0.f,0.f,0.f};
      f4v a41 = {0.f,0.f,0.f,0.f};
#pragma unroll
      for (int kc=0;kc<4;kc++){
        s8v af = *(const s8v*)(sA2f + ((dt*4+kc)*64 + l)*8);
        a40 = __builtin_amdgcn_mfma_f32_16x16x32_bf16(af, bfr0[kc], a40, 0, 0, 0);
        a41 = __builtin_amdgcn_mfma_f32_16x16x32_bf16(af, bfr1[kc], a41, 0, 0, 0);
      }
      float4 a3v = *(const float4*)(A3 + dt*16 + kg*4);
      sacc0 += fmaxf(a40[0],0.f)*a3v.x + fmaxf(a40[1],0.f)*a3v.y
             + fmaxf(a40[2],0.f)*a3v.z + fmaxf(a40[3],0.f)*a3v.w;
      sacc1 += fmaxf(a41[0],0.f)*a3v.x + fmaxf(a41[1],0.f)*a3v.y
             + fmaxf(a41[2],0.f)*a3v.z + fmaxf(a41[3],0.f)*a3v.w;
    }
    sacc0 += __shfl_xor(sacc0, 16); sacc0 += __shfl_xor(sacc0, 32);
    sacc1 += __shfl_xor(sacc1, 16); sacc1 += __shfl_xor(sacc1, 32);
    if (l < 16){
      int c0 = (w*2+0)*16 + l;
      int c1 = (w*2+1)*16 + l;
      sSC[c0>>6][c0&63] = 1.f/(1.f + __expf(-sacc0));
      sSC[c1>>6][c1&63] = 1.f/(1.f + __expf(-sacc1));
    }
  }
  __syncthreads();

  if (w < 4){ // softmax: wave w -> b = blk*4 + w
    int b = blk*4 + w;
    int4 ra = *(const int4*)(R1g + (size_t)b*256 + l*4);
    float e0 = __expf(sSC[w][32 + ra.x]);
    float e1 = __expf(sSC[w][32 + ra.y]);
    float e2 = __expf(sSC[w][32 + ra.z]);
    float e3 = __expf(sSC[w][32 + ra.w]);
    float s = e0+e1+e2+e3;
    for (int m=1;m<64;m<<=1) s += __shfl_xor(s, m);
    float inv = 1.f/s;
    float4 o = { e0*inv, e1*inv, e2*inv, e3*inv };
    *(float4*)(W1g + (size_t)b*256 + l*4) = o;
    if (l < 16){
      float ee = __expf(sSC[w][R0g[b*16 + l]]);
      float s0 = ee;
      for (int m=1;m<16;m<<=1) s0 += __shfl_xor(s0, m);
      W0g[b*16 + l] = ee/s0;
    }
  }
}

// ---------------- weighted gathers: hop-1 bf16, hop-2 fp8 -> SV
__global__ __launch_bounds__(256) void k_sv2(const int* __restrict__ E1g,
                                             const int* __restrict__ E2g,
                                             const float* __restrict__ W0g,
                                             const float* __restrict__ W1g,
                                             const unsigned* __restrict__ entB,
                                             const unsigned short* __restrict__ entF,
                                             float* __restrict__ SV){
  int b = blockIdx.x, t = threadIdx.x, l = t&63, w = t>>6;
  __shared__ float sW0[16];
  __shared__ float sW1[256];
  __shared__ int sE1[16];
  __shared__ int sE2[256];
  __shared__ float sPart[4][128];
  if (t < 16){ sE1[t] = E1g[b*16+t]; sW0[t] = W0g[b*16+t]; }
  sE2[t] = E2g[b*256+t];
  sW1[t] = W1g[b*256+t];
  __syncthreads();

  float2 a0 = {0.f,0.f};
#pragma unroll
  for (int i=0;i<4;i++){
    int row = w*4 + i;
    float f = sW0[row];
    unsigned pk = entB[(size_t)sE1[row]*64 + l];
    a0.x += f*lo2f(pk); a0.y += f*hi2f(pk);
  }
  float2 a1 = {0.f,0.f};
#pragma unroll 4
  for (int i=0;i<64;i++){
    int row = w*64 + i;
    float f = sW1[row];
    int q = (int)entF[(size_t)sE2[row]*64 + l];
    float fx = __builtin_amdgcn_cvt_f32_fp8(q, 0);
    float fy = __builtin_amdgcn_cvt_f32_fp8(q, 1);
    a1.x += f*fx; a1.y += f*fy;
  }
  *(float2*)&sPart[w][2*l] = a0;
  __syncthreads();
  if (t < 128) SV[((size_t)b*2 + 0)*128 + t] = sPart[0][t]+sPart[1][t]+sPart[2][t]+sPart[3][t];
  __syncthreads();
  *(float2*)&sPart[w][2*l] = a1;
  __syncthreads();
  if (t < 128) SV[((size_t)b*2 + 1)*128 + t] = sPart[0][t]+sPart[1][t]+sPart[2][t]+sPart[3][t];
}

// ---------------- MFMA vagg (unchanged)
__global__ __launch_bounds__(256) void k_vagg2(const float* __restrict__ SV,
                                               const float* __restrict__ Hb,
                                               const float* __restrict__ S1,
                                               const unsigned short* __restrict__ WxF,
                                               const float* __restrict__ Wxb,
                                               const unsigned short* __restrict__ W1F,
                                               const float* __restrict__ W1b,
                                               const unsigned short* __restrict__ W2F,
                                               const float* __restrict__ W2b,
                                               float* __restrict__ out){
  int b0 = blockIdx.x * 32;
  int iter = blockIdx.y;
  int t = threadIdx.x, l = t&63, w = t>>6;
  int wm = w>>1, wn = w&1;
  __shared__ __align__(16) unsigned short sSV[32*128];
  __shared__ __align__(16) unsigned short sA [32*128];
  __shared__ __align__(16) unsigned short sV [32*256];
  char* sSVb = (char*)sSV; char* sAb = (char*)sA; char* sVb = (char*)sV;

  const float* anc = iter ? S1 : Hb;
  {
    int row = t>>3, c0 = (t&7)*16;
    const float* ps = SV + ((size_t)(b0+row)*2 + iter)*128 + c0;
    const float* pa = anc + (size_t)(b0+row)*128 + c0;
    int xo = (row&7)<<4;
#pragma unroll
    for (int c2=0;c2<8;c2++){
      float2 sv2 = *(const float2*)(ps + c2*2);
      float2 an2 = *(const float2*)(pa + c2*2);
      unsigned pv  = (unsigned)f2bf(sv2.x) | ((unsigned)f2bf(sv2.y)<<16);
      unsigned pan = (unsigned)f2bf(an2.x) | ((unsigned)f2bf(an2.y)<<16);
      int byte = (row*256 + c0*2 + c2*4) ^ xo;
      *(unsigned*)(sSVb + byte) = pv;
      *(unsigned*)(sAb  + byte) = pan;
    }
  }
  __syncthreads();

  int kl = l&15, kg = l>>4;
  {
    int rowg = wm*16 + kl;
    int xo = (rowg&7)<<4;
    s8v af[4];
#pragma unroll
    for (int kc=0;kc<4;kc++)
      af[kc] = *(const s8v*)(sSVb + ((rowg*256 + kc*64 + kg*16) ^ xo));
#pragma unroll
    for (int nt8=0;nt8<8;nt8++){
      int ntg = wn*8 + nt8;
      int n = ntg*16 + kl;
      float bias = Wxb[iter*256 + n];
      f4v acc = {bias,bias,bias,bias};
#pragma unroll
      for (int kc=0;kc<4;kc++){
        s8v bf = *(const s8v*)(WxF + ((size_t)(((iter*16 + ntg)*4 + kc)*64 + l))*8);
        acc = __builtin_amdgcn_mfma_f32_16x16x32_bf16(af[kc], bf, acc, 0, 0, 0);
      }
#pragma unroll
      for (int r=0;r<4;r++){
        int rowl = wm*16 + kg*4 + r;
        int byte = (rowl*512 + n*2) ^ ((rowl&7)<<4);
        *(unsigned short*)(sVb + byte) = f2bf(leakyf(acc[r]));
      }
    }
  }
  __syncthreads();
  {
    int rowl = wm*16 + kl;
    int xo = (rowl&7)<<4;
    s8v x1f[8], x2f[8];
#pragma unroll
    for (int kc=0;kc<8;kc++){
      int k0 = kc*32 + kg*8;
      s8v vv = *(const s8v*)(sVb + ((rowl*512 + k0*2) ^ xo));
      s8v aa = *(const s8v*)(sAb + ((rowl*256 + (k0&127)*2) ^ xo));
#pragma unroll
      for (int j=0;j<8;j++){
        float vf = bf2f((unsigned short)vv[j]);
        float av = bf2f((unsigned short)aa[j]);
        x1f[kc][j] = (short)f2bf(av + vf);
        x2f[kc][j] = (short)f2bf(av * vf);
      }
    }
    int obase = iter ? 0 : 256;
#pragma unroll
    for (int nt8=0;nt8<8;nt8++){
      int ntg = wn*8 + nt8;
      int n = ntg*16 + kl;
      float bb1 = W1b[n], bb2 = W2b[n];
      f4v a1 = {bb1,bb1,bb1,bb1};
      f4v a2 = {bb2,bb2,bb2,bb2};
#pragma unroll
      for (int kc=0;kc<8;kc++){
        s8v wf1 = *(const s8v*)(W1F + ((size_t)((ntg*8 + kc)*64 + l))*8);
        a1 = __builtin_amdgcn_mfma_f32_16x16x32_bf16(x1f[kc], wf1, a1, 0, 0, 0);
      }
#pragma unroll
      for (int kc=0;kc<8;kc++){
        s8v wf2 = *(const s8v*)(W2F + ((size_t)((ntg*8 + kc)*64 + l))*8);
        a2 = __builtin_amdgcn_mfma_f32_16x16x32_bf16(x2f[kc], wf2, a2, 0, 0, 0);
      }
#pragma unroll
      for (int r=0;r<4;r++){
        int row = wm*16 + kg*4 + r;
        out[(size_t)(b0+row)*640 + obase + n] = leakyf(a1[r]) + leakyf(a2[r]);
      }
    }
  }
}

extern "C" void kernel_launch(void* const* d_in, const int* in_sizes, int n_in,
                              void* d_out, int out_size, void* d_ws, size_t ws_size,
                              hipStream_t stream) {
  const int*   eidx = (const int*)d_in[0];
  const int*   adjE = (const int*)d_in[1];
  const int*   adjR = (const int*)d_in[2];
  const float* ent  = (const float*)d_in[3];
  const float* rel  = (const float*)d_in[4];
  const float* A1   = (const float*)d_in[5];
  const float* A2   = (const float*)d_in[6];
  const float* A3   = (const float*)d_in[7];
  const float* Wxw  = (const float*)d_in[8];
  const float* Wxb  = (const float*)d_in[9];
  const float* W1w  = (const float*)d_in[10];
  const float* W1b  = (const float*)d_in[11];
  const float* W2w  = (const float*)d_in[12];
  const float* W2b  = (const float*)d_in[13];
  float* out = (float*)d_out;

  char* wsb = (char*)d_ws;
  size_t off = 0;
  auto alloc = [&](size_t bytes)->char*{
    char* p = wsb + off; off += (bytes + 255) & ~(size_t)255; return p;
  };
  float* Pg   = (float*)alloc(NREL*DIM*4);
  unsigned short* A1Lf = (unsigned short*)alloc(2048*8*2);
  unsigned short* A2f  = (unsigned short*)alloc(2048*8*2);
  unsigned short* WxF = (unsigned short*)alloc((size_t)8192*8*2);
  unsigned short* W1F = (unsigned short*)alloc((size_t)8192*8*2);
  unsigned short* W2F = (unsigned short*)alloc((size_t)8192*8*2);
  unsigned* entB = (unsigned*)alloc((size_t)NENT*64*4);
  unsigned short* entF = (unsigned short*)alloc((size_t)NENT*64*2);
  unsigned* ANb  = (unsigned*)alloc((size_t)NB*2*64*4);
  float* Hb = (float*)alloc((size_t)NB*DIM*4);
  float* S1 = (float*)alloc((size_t)NB*DIM*4);
  float* SV = (float*)alloc((size_t)NB*2*DIM*4);
  int* E1g = (int*)alloc((size_t)NB*16*4);
  int* E2g = (int*)alloc((size_t)NB*256*4);
  int* R0g = (int*)alloc((size_t)NB*16*4);
  int* R1g = (int*)alloc((size_t)NB*256*4);
  float* W0g = (float*)alloc((size_t)NB*16*4);
  float* W1g = (float*)alloc((size_t)NB*256*4);

  k_init<<<dim3(SCALE_BLKS + 144), dim3(256), 0, stream>>>(
      ent, rel, A1, A2, Wxw, W1w, W2w,
      entB, entF, Pg, A1Lf, A2f, WxF, W1F, W2F);
  k_gath<<<dim3(NB),     dim3(64), 0, stream>>>(eidx, adjE, adjR, entB,
                                                E1g, E2g, R0g, R1g, ANb, Hb, S1, out);
  k_score2<<<dim3(NB/4), dim3(512), 0, stream>>>(ANb, A1Lf, Pg, A2f, A3,
                                                 R0g, R1g, W0g, W1g);
  k_sv2 <<<dim3(NB),     dim3(256), 0, stream>>>(E1g, E2g, W0g, W1g, entB, entF, SV);
  k_vagg2<<<dim3(NB/32, 2), dim3(256), 0, stream>>>(SV, Hb, S1, WxF, Wxb,
                                                    W1F, W1b, W2F, W2b, out);
}

// Round 13
// 64.471 us; speedup vs baseline: 1.4896x; 1.1666x over previous
//
#include <hip/hip_runtime.h>

#define NENT 100000
#define NREL 32
#define DIM  128
#define NB   2048

typedef short s8v __attribute__((ext_vector_type(8)));
typedef float f4v __attribute__((ext_vector_type(4)));

__device__ __forceinline__ unsigned short f2bf(float x){
  unsigned u = __float_as_uint(x);
  return (unsigned short)((u + 0x7fffu + ((u>>16)&1u)) >> 16);
}
__device__ __forceinline__ float bf2f(unsigned short u){
  return __uint_as_float(((unsigned)u) << 16);
}
__device__ __forceinline__ float lo2f(unsigned p){ return __uint_as_float(p << 16); }
__device__ __forceinline__ float hi2f(unsigned p){ return __uint_as_float(p & 0xffff0000u); }
__device__ __forceinline__ float leakyf(float x){ return x > 0.f ? x : 0.2f*x; }

#define GATH_BLKS  512
#define SCALE_BLKS 25000

// ---------------- initgath: gath (raw-ent renorm) ∥ scale→entF ∥ prep — no cross-block deps
__global__ __launch_bounds__(256) void k_initgath(const int* __restrict__ eidx,
                                                  const int* __restrict__ adjE,
                                                  const int* __restrict__ adjR,
                                                  const float* __restrict__ ent,
                                                  const float* __restrict__ rel,
                                                  const float* __restrict__ A1,
                                                  const float* __restrict__ A2,
                                                  const float* __restrict__ Wxw,
                                                  const float* __restrict__ W1w,
                                                  const float* __restrict__ W2w,
                                                  unsigned short* __restrict__ entF,
                                                  float* __restrict__ Pg,
                                                  unsigned short* __restrict__ A1Lf,
                                                  unsigned short* __restrict__ A2f,
                                                  unsigned short* __restrict__ WxF,
                                                  unsigned short* __restrict__ W1F,
                                                  unsigned short* __restrict__ W2F,
                                                  int* __restrict__ E1g, int* __restrict__ E2g,
                                                  int* __restrict__ R0g, int* __restrict__ R1g,
                                                  unsigned* __restrict__ ANb,
                                                  float* __restrict__ Hb, float* __restrict__ S1,
                                                  float* __restrict__ out){
  int t = threadIdx.x;
  __shared__ float srn[2][128];
  __shared__ float red[2][2];
  if (blockIdx.x < GATH_BLKS){
    // ---- gather: wave w -> b = blk*4 + w ; barrier-free, raw-ent renorm
    int w = t>>6, l = t&63;
    int b = blockIdx.x*4 + w;
    int idx = eidx[b];
    int e1 = 0;
    if (l < 16){
      e1 = adjE[idx*16 + l];
      E1g[b*16+l] = e1;
      R0g[b*16+l] = adjR[idx*16 + l];
    }
    int esrc = __shfl(e1, l>>2);
    int4 e2 = *(const int4*)(adjE + (size_t)esrc*16 + (l&3)*4);
    int4 r1 = *(const int4*)(adjR + (size_t)esrc*16 + (l&3)*4);
    *(int4*)(E2g + (size_t)b*256 + l*4) = e2;
    *(int4*)(R1g + (size_t)b*256 + l*4) = r1;
    // batch-issue all 17 row loads, then reduce
    float2 hv = *(const float2*)(ent + (size_t)idx*128 + 2*l);
    float2 rv[16];
#pragma unroll
    for (int i=0;i<16;i++){
      int e = __shfl(e1, i);
      rv[i] = *(const float2*)(ent + (size_t)e*128 + 2*l);
    }
    float ssh = hv.x*hv.x + hv.y*hv.y;
    for (int m=1;m<64;m<<=1) ssh += __shfl_xor(ssh, m);
    float sch = fminf(1.f, 1.f/(sqrtf(ssh) + 1e-7f));
    hv.x *= sch; hv.y *= sch;
    float sx = 0.f, sy = 0.f;
#pragma unroll
    for (int i=0;i<16;i++){
      float ss = rv[i].x*rv[i].x + rv[i].y*rv[i].y;
      for (int m=1;m<64;m<<=1) ss += __shfl_xor(ss, m);
      float sc = fminf(1.f, 1.f/(sqrtf(ss) + 1e-7f));
      sx += sc*rv[i].x; sy += sc*rv[i].y;
    }
    ANb[((size_t)b*2 + 0)*64 + l] = (unsigned)f2bf(hv.x) | ((unsigned)f2bf(hv.y) << 16);
    ANb[((size_t)b*2 + 1)*64 + l] = (unsigned)f2bf(sx) | ((unsigned)f2bf(sy) << 16);
    *(float2*)(Hb + (size_t)b*128 + 2*l) = hv;
    *(float2*)(out + (size_t)b*640 + 512 + 2*l) = hv;
    float2 sv = { sx, sy };
    *(float2*)(S1 + (size_t)b*128 + 2*l) = sv;
    return;
  }
  if (blockIdx.x < GATH_BLKS + SCALE_BLKS){
    int row = (blockIdx.x - GATH_BLKS)*4 + (t>>6);
    if (row >= NENT) return;
    int l = t & 63;
    float2 v = *(const float2*)(ent + (size_t)row*128 + 2*l);
    float ss = v.x*v.x + v.y*v.y;
    for (int m=1;m<64;m<<=1) ss += __shfl_xor(ss, m);
    float sc = fminf(1.f, 1.f/(sqrtf(ss) + 1e-7f));
    int p8 = __builtin_amdgcn_cvt_pk_fp8_f32(sc*v.x, sc*v.y, 0, false);
    entF[(size_t)row*64 + l] = (unsigned short)p8;
    return;
  }
  int half = t>>7, tt = t&127;
  int blk = (blockIdx.x - GATH_BLKS - SCALE_BLKS)*2 + half;
  if (blk < 32){
    int r = blk;
    float v = rel[r*128 + tt];
    float ss = v*v;
    for (int m=1;m<64;m<<=1) ss += __shfl_xor(ss, m);
    if ((tt&63)==0) red[half][tt>>6] = ss;
    __syncthreads();
    float nrm = sqrtf(red[half][0]+red[half][1]);
    float f = fminf(1.f, 1.f/(nrm + 1e-7f));
    srn[half][tt] = v*f;
    __syncthreads();
    const float4* ar = (const float4*)(A1 + tt*256 + 128);
    float acc = 0.f;
#pragma unroll
    for (int k4=0;k4<32;k4++){
      float4 a = ar[k4];
      acc += a.x*srn[half][k4*4] + a.y*srn[half][k4*4+1]
           + a.z*srn[half][k4*4+2] + a.w*srn[half][k4*4+3];
    }
    Pg[r*128 + tt] = acc;
  } else if (blk < 64){
    int bb = blk - 32;
    int fid = bb*64 + (tt>>1);
    int hf = tt&1;
    int lane = fid & 63, kc = (fid>>6)&3, dt = fid>>8;
    int d = dt*16 + (lane&15);
    int kb = kc*32 + ((lane>>4)&3)*8 + hf*4;
#pragma unroll
    for (int i=0;i<4;i++)
      A2f[fid*8 + hf*4 + i] = f2bf(A2[d*128 + kb + i]);
  } else if (blk < 96){
    int bb = blk - 64;
    int fid = bb*64 + (tt>>1);
    int hf = tt&1;
    int lane = fid & 63, kc = (fid>>6)&3, dt = fid>>8;
    int d = dt*16 + (lane&15);
    int kb = kc*32 + ((lane>>4)&3)*8 + hf*4;
#pragma unroll
    for (int i=0;i<4;i++)
      A1Lf[fid*8 + hf*4 + i] = f2bf(A1[d*256 + kb + i]);
  } else if (blk < 160){
    int fid = (blk-96)*128 + tt;
    int l = fid&63, kc = (fid>>6)&3, nt = (fid>>8)&15, iter = (fid>>12)&1;
    int n = nt*16 + (l&15);
    int k = kc*32 + ((l>>4)&3)*8;
    const float* src = Wxw + ((size_t)((iter*2 + (n>>7))*128 + (n&127)))*128 + k;
#pragma unroll
    for (int j=0;j<8;j++) WxF[(size_t)fid*8 + j] = f2bf(src[j]);
  } else if (blk < 224){
    int fid = (blk-160)*128 + tt;
    int l = fid&63, kc = (fid>>6)&7, nt = (fid>>9)&15;
    int n = nt*16 + (l&15);
    int k = kc*32 + ((l>>4)&3)*8;
#pragma unroll
    for (int j=0;j<8;j++) W1F[(size_t)fid*8 + j] = f2bf(W1w[(size_t)n*256 + k + j]);
  } else {
    int fid = (blk-224)*128 + tt;
    int l = fid&63, kc = (fid>>6)&7, nt = (fid>>9)&15;
    int n = nt*16 + (l&15);
    int k = kc*32 + ((l>>4)&3)*8;
#pragma unroll
    for (int j=0;j<8;j++) W2F[(size_t)fid*8 + j] = f2bf(W2w[(size_t)n*256 + k + j]);
  }
}

// ---------------- batched scores: 4 b/block, 8 waves, A2f LDS-staged
__global__ __launch_bounds__(512) void k_score2(const unsigned* __restrict__ ANb,
                                                const unsigned short* __restrict__ A1Lf,
                                                const float* __restrict__ Pg,
                                                const unsigned short* __restrict__ A2f,
                                                const float* __restrict__ A3,
                                                const int* __restrict__ R0g,
                                                const int* __restrict__ R1g,
                                                float* __restrict__ W0g,
                                                float* __restrict__ W1g){
  int blk = blockIdx.x;              // 4 b per block
  int t = threadIdx.x, l = t&63, w = t>>6;   // 8 waves
  __shared__ __align__(16) unsigned short sA2f[2048*8];  // 32 KB
  __shared__ __align__(16) unsigned sAN[16*64];          // 8 anchors (rows 8..15 zero), swizzled
  __shared__ float sC[8][132];
  __shared__ float sSC[4][64];

  { // stage A2f (32 KB, 4 uint4/thread) + anchors
    const uint4* src = (const uint4*)A2f;
    uint4* dst = (uint4*)sA2f;
#pragma unroll
    for (int i=0;i<4;i++) dst[t + i*512] = src[t + i*512];
    if (t < 256){
      int row = t>>4, seg = t&15;
      uint4 v = {0u,0u,0u,0u};
      if (row < 8) v = *(const uint4*)(ANb + ((size_t)blk*8 + row)*64 + seg*4);
      *(uint4*)((char*)sAN + ((row*256 + seg*16) ^ ((row&7)<<4))) = v;
    }
  }
  __syncthreads();

  int cl = l&15, kg = l>>4;
  { // G1: c = A1L @ anchors ; wave w -> dt = w
    s8v bf[4];
#pragma unroll
    for (int kc=0;kc<4;kc++)
      bf[kc] = *(const s8v*)((const char*)sAN + ((cl*256 + (kc*32+kg*8)*2) ^ ((cl&7)<<4)));
    int dt = w;
    f4v acc = {0.f,0.f,0.f,0.f};
#pragma unroll
    for (int kc=0;kc<4;kc++){
      s8v af = *(const s8v*)(A1Lf + ((size_t)((dt*4+kc)*64 + l))*8);
      acc = __builtin_amdgcn_mfma_f32_16x16x32_bf16(af, bf[kc], acc, 0, 0, 0);
    }
    if (cl < 8){
#pragma unroll
      for (int r=0;r<4;r++) sC[cl][dt*16 + kg*4 + r] = acc[r];
    }
  }
  __syncthreads();

  { // G2: wave w -> anchor ci = w ; cc splits relations (rr = cc*16+cl)
    s8v bfr0[4], bfr1[4];
#pragma unroll
    for (int cc=0; cc<2; cc++){
      int ci = w;
      int rr = cc*16 + cl;
      s8v* bfr = cc ? bfr1 : bfr0;
#pragma unroll
      for (int kc=0;kc<4;kc++){
        int k0 = kc*32 + kg*8;
        float4 pa = *(const float4*)(Pg + rr*128 + k0);
        float4 pb = *(const float4*)(Pg + rr*128 + k0 + 4);
        bfr[kc][0] = (short)f2bf(fmaxf(sC[ci][k0+0]+pa.x, 0.f));
        bfr[kc][1] = (short)f2bf(fmaxf(sC[ci][k0+1]+pa.y, 0.f));
        bfr[kc][2] = (short)f2bf(fmaxf(sC[ci][k0+2]+pa.z, 0.f));
        bfr[kc][3] = (short)f2bf(fmaxf(sC[ci][k0+3]+pa.w, 0.f));
        bfr[kc][4] = (short)f2bf(fmaxf(sC[ci][k0+4]+pb.x, 0.f));
        bfr[kc][5] = (short)f2bf(fmaxf(sC[ci][k0+5]+pb.y, 0.f));
        bfr[kc][6] = (short)f2bf(fmaxf(sC[ci][k0+6]+pb.z, 0.f));
        bfr[kc][7] = (short)f2bf(fmaxf(sC[ci][k0+7]+pb.w, 0.f));
      }
    }
    float sacc0 = 0.f, sacc1 = 0.f;
#pragma unroll
    for (int dt=0; dt<8; dt++){
      f4v a40 = {0.f,0.f,0.f,0.f};
      f4v a41 = {0.f,0.f,0.f,0.f};
#pragma unroll
      for (int kc=0;kc<4;kc++){
        s8v af = *(const s8v*)(sA2f + ((dt*4+kc)*64 + l)*8);
        a40 = __builtin_amdgcn_mfma_f32_16x16x32_bf16(af, bfr0[kc], a40, 0, 0, 0);
        a41 = __builtin_amdgcn_mfma_f32_16x16x32_bf16(af, bfr1[kc], a41, 0, 0, 0);
      }
      float4 a3v = *(const float4*)(A3 + dt*16 + kg*4);
      sacc0 += fmaxf(a40[0],0.f)*a3v.x + fmaxf(a40[1],0.f)*a3v.y
             + fmaxf(a40[2],0.f)*a3v.z + fmaxf(a40[3],0.f)*a3v.w;
      sacc1 += fmaxf(a41[0],0.f)*a3v.x + fmaxf(a41[1],0.f)*a3v.y
             + fmaxf(a41[2],0.f)*a3v.z + fmaxf(a41[3],0.f)*a3v.w;
    }
    sacc0 += __shfl_xor(sacc0, 16); sacc0 += __shfl_xor(sacc0, 32);
    sacc1 += __shfl_xor(sacc1, 16); sacc1 += __shfl_xor(sacc1, 32);
    if (l < 16){
      int c0 = (w*2+0)*16 + l;
      int c1 = (w*2+1)*16 + l;
      sSC[c0>>6][c0&63] = 1.f/(1.f + __expf(-sacc0));
      sSC[c1>>6][c1&63] = 1.f/(1.f + __expf(-sacc1));
    }
  }
  __syncthreads();

  if (w < 4){ // softmax: wave w -> b = blk*4 + w
    int b = blk*4 + w;
    int4 ra = *(const int4*)(R1g + (size_t)b*256 + l*4);
    float e0 = __expf(sSC[w][32 + ra.x]);
    float e1 = __expf(sSC[w][32 + ra.y]);
    float e2 = __expf(sSC[w][32 + ra.z]);
    float e3 = __expf(sSC[w][32 + ra.w]);
    float s = e0+e1+e2+e3;
    for (int m=1;m<64;m<<=1) s += __shfl_xor(s, m);
    float inv = 1.f/s;
    float4 o = { e0*inv, e1*inv, e2*inv, e3*inv };
    *(float4*)(W1g + (size_t)b*256 + l*4) = o;
    if (l < 16){
      float ee = __expf(sSC[w][R0g[b*16 + l]]);
      float s0 = ee;
      for (int m=1;m<16;m<<=1) s0 += __shfl_xor(s0, m);
      W0g[b*16 + l] = ee/s0;
    }
  }
}

// ---------------- weighted gathers: both hops fp8 -> SV
__global__ __launch_bounds__(256) void k_sv2(const int* __restrict__ E1g,
                                             const int* __restrict__ E2g,
                                             const float* __restrict__ W0g,
                                             const float* __restrict__ W1g,
                                             const unsigned short* __restrict__ entF,
                                             float* __restrict__ SV){
  int b = blockIdx.x, t = threadIdx.x, l = t&63, w = t>>6;
  __shared__ float sW0[16];
  __shared__ float sW1[256];
  __shared__ int sE1[16];
  __shared__ int sE2[256];
  __shared__ float sPart[4][128];
  if (t < 16){ sE1[t] = E1g[b*16+t]; sW0[t] = W0g[b*16+t]; }
  sE2[t] = E2g[b*256+t];
  sW1[t] = W1g[b*256+t];
  __syncthreads();

  float2 a0 = {0.f,0.f};
#pragma unroll
  for (int i=0;i<4;i++){
    int row = w*4 + i;
    float f = sW0[row];
    int q = (int)entF[(size_t)sE1[row]*64 + l];
    a0.x += f*__builtin_amdgcn_cvt_f32_fp8(q, 0);
    a0.y += f*__builtin_amdgcn_cvt_f32_fp8(q, 1);
  }
  float2 a1 = {0.f,0.f};
#pragma unroll 4
  for (int i=0;i<64;i++){
    int row = w*64 + i;
    float f = sW1[row];
    int q = (int)entF[(size_t)sE2[row]*64 + l];
    a1.x += f*__builtin_amdgcn_cvt_f32_fp8(q, 0);
    a1.y += f*__builtin_amdgcn_cvt_f32_fp8(q, 1);
  }
  *(float2*)&sPart[w][2*l] = a0;
  __syncthreads();
  if (t < 128) SV[((size_t)b*2 + 0)*128 + t] = sPart[0][t]+sPart[1][t]+sPart[2][t]+sPart[3][t];
  __syncthreads();
  *(float2*)&sPart[w][2*l] = a1;
  __syncthreads();
  if (t < 128) SV[((size_t)b*2 + 1)*128 + t] = sPart[0][t]+sPart[1][t]+sPart[2][t]+sPart[3][t];
}

// ---------------- MFMA vagg: 16-row tiles, grid (128, 2) — all CUs busy
__global__ __launch_bounds__(256) void k_vagg2(const float* __restrict__ SV,
                                               const float* __restrict__ Hb,
                                               const float* __restrict__ S1,
                                               const unsigned short* __restrict__ WxF,
                                               const float* __restrict__ Wxb,
                                               const unsigned short* __restrict__ W1F,
                                               const float* __restrict__ W1b,
                                               const unsigned short* __restrict__ W2F,
                                               const float* __restrict__ W2b,
                                               float* __restrict__ out){
  int b0 = blockIdx.x * 16;
  int iter = blockIdx.y;
  int t = threadIdx.x, l = t&63, w = t>>6;
  __shared__ __align__(16) unsigned short sSV[16*128];
  __shared__ __align__(16) unsigned short sA [16*128];
  __shared__ __align__(16) unsigned short sV [16*256];
  char* sSVb = (char*)sSV; char* sAb = (char*)sA; char* sVb = (char*)sV;

  const float* anc = iter ? S1 : Hb;
  {
    int row = t>>4, c0 = (t&15)*8;
    const float* ps = SV + ((size_t)(b0+row)*2 + iter)*128 + c0;
    const float* pa = anc + (size_t)(b0+row)*128 + c0;
    int xo = (row&7)<<4;
#pragma unroll
    for (int c2=0;c2<4;c2++){
      float2 sv2 = *(const float2*)(ps + c2*2);
      float2 an2 = *(const float2*)(pa + c2*2);
      unsigned pv  = (unsigned)f2bf(sv2.x) | ((unsigned)f2bf(sv2.y)<<16);
      unsigned pan = (unsigned)f2bf(an2.x) | ((unsigned)f2bf(an2.y)<<16);
      int byte = (row*256 + c0*2 + c2*4) ^ xo;
      *(unsigned*)(sSVb + byte) = pv;
      *(unsigned*)(sAb  + byte) = pan;
    }
  }
  __syncthreads();

  int kl = l&15, kg = l>>4;
  { // G1: wave w -> col-tiles ntg = w*4..w*4+3 (rows 0..15)
    int rowg = kl;
    int xo = (rowg&7)<<4;
    s8v af[4];
#pragma unroll
    for (int kc=0;kc<4;kc++)
      af[kc] = *(const s8v*)(sSVb + ((rowg*256 + kc*64 + kg*16) ^ xo));
#pragma unroll
    for (int nt4=0;nt4<4;nt4++){
      int ntg = w*4 + nt4;
      int n = ntg*16 + kl;
      float bias = Wxb[iter*256 + n];
      f4v acc = {bias,bias,bias,bias};
#pragma unroll
      for (int kc=0;kc<4;kc++){
        s8v bf = *(const s8v*)(WxF + ((size_t)(((iter*16 + ntg)*4 + kc)*64 + l))*8);
        acc = __builtin_amdgcn_mfma_f32_16x16x32_bf16(af[kc], bf, acc, 0, 0, 0);
      }
#pragma unroll
      for (int r=0;r<4;r++){
        int rowl = kg*4 + r;
        int byte = (rowl*512 + n*2) ^ ((rowl&7)<<4);
        *(unsigned short*)(sVb + byte) = f2bf(leakyf(acc[r]));
      }
    }
  }
  __syncthreads();
  {
    int rowl = kl;
    int xo = (rowl&7)<<4;
    s8v x1f[8], x2f[8];
#pragma unroll
    for (int kc=0;kc<8;kc++){
      int k0 = kc*32 + kg*8;
      s8v vv = *(const s8v*)(sVb + ((rowl*512 + k0*2) ^ xo));
      s8v aa = *(const s8v*)(sAb + ((rowl*256 + (k0&127)*2) ^ xo));
#pragma unroll
      for (int j=0;j<8;j++){
        float vf = bf2f((unsigned short)vv[j]);
        float av = bf2f((unsigned short)aa[j]);
        x1f[kc][j] = (short)f2bf(av + vf);
        x2f[kc][j] = (short)f2bf(av * vf);
      }
    }
    int obase = iter ? 0 : 256;
#pragma unroll
    for (int nt4=0;nt4<4;nt4++){
      int ntg = w*4 + nt4;
      int n = ntg*16 + kl;
      float bb1 = W1b[n], bb2 = W2b[n];
      f4v a1 = {bb1,bb1,bb1,bb1};
      f4v a2 = {bb2,bb2,bb2,bb2};
#pragma unroll
      for (int kc=0;kc<8;kc++){
        s8v wf1 = *(const s8v*)(W1F + ((size_t)((ntg*8 + kc)*64 + l))*8);
        a1 = __builtin_amdgcn_mfma_f32_16x16x32_bf16(x1f[kc], wf1, a1, 0, 0, 0);
      }
#pragma unroll
      for (int kc=0;kc<8;kc++){
        s8v wf2 = *(const s8v*)(W2F + ((size_t)((ntg*8 + kc)*64 + l))*8);
        a2 = __builtin_amdgcn_mfma_f32_16x16x32_bf16(x2f[kc], wf2, a2, 0, 0, 0);
      }
#pragma unroll
      for (int r=0;r<4;r++){
        int row = kg*4 + r;
        out[(size_t)(b0+row)*640 + obase + n] = leakyf(a1[r]) + leakyf(a2[r]);
      }
    }
  }
}

extern "C" void kernel_launch(void* const* d_in, const int* in_sizes, int n_in,
                              void* d_out, int out_size, void* d_ws, size_t ws_size,
                              hipStream_t stream) {
  const int*   eidx = (const int*)d_in[0];
  const int*   adjE = (const int*)d_in[1];
  const int*   adjR = (const int*)d_in[2];
  const float* ent  = (const float*)d_in[3];
  const float* rel  = (const float*)d_in[4];
  const float* A1   = (const float*)d_in[5];
  const float* A2   = (const float*)d_in[6];
  const float* A3   = (const float*)d_in[7];
  const float* Wxw  = (const float*)d_in[8];
  const float* Wxb  = (const float*)d_in[9];
  const float* W1w  = (const float*)d_in[10];
  const float* W1b  = (const float*)d_in[11];
  const float* W2w  = (const float*)d_in[12];
  const float* W2b  = (const float*)d_in[13];
  float* out = (float*)d_out;

  char* wsb = (char*)d_ws;
  size_t off = 0;
  auto alloc = [&](size_t bytes)->char*{
    char* p = wsb + off; off += (bytes + 255) & ~(size_t)255; return p;
  };
  float* Pg   = (float*)alloc(NREL*DIM*4);
  unsigned short* A1Lf = (unsigned short*)alloc(2048*8*2);
  unsigned short* A2f  = (unsigned short*)alloc(2048*8*2);
  unsigned short* WxF = (unsigned short*)alloc((size_t)8192*8*2);
  unsigned short* W1F = (unsigned short*)alloc((size_t)8192*8*2);
  unsigned short* W2F = (unsigned short*)alloc((size_t)8192*8*2);
  unsigned short* entF = (unsigned short*)alloc((size_t)NENT*64*2);
  unsigned* ANb  = (unsigned*)alloc((size_t)NB*2*64*4);
  float* Hb = (float*)alloc((size_t)NB*DIM*4);
  float* S1 = (float*)alloc((size_t)NB*DIM*4);
  float* SV = (float*)alloc((size_t)NB*2*DIM*4);
  int* E1g = (int*)alloc((size_t)NB*16*4);
  int* E2g = (int*)alloc((size_t)NB*256*4);
  int* R0g = (int*)alloc((size_t)NB*16*4);
  int* R1g = (int*)alloc((size_t)NB*256*4);
  float* W0g = (float*)alloc((size_t)NB*16*4);
  float* W1g = (float*)alloc((size_t)NB*256*4);

  k_initgath<<<dim3(GATH_BLKS + SCALE_BLKS + 144), dim3(256), 0, stream>>>(
      eidx, adjE, adjR, ent, rel, A1, A2, Wxw, W1w, W2w,
      entF, Pg, A1Lf, A2f, WxF, W1F, W2F,
      E1g, E2g, R0g, R1g, ANb, Hb, S1, out);
  k_score2<<<dim3(NB/4), dim3(512), 0, stream>>>(ANb, A1Lf, Pg, A2f, A3,
                                                 R0g, R1g, W0g, W1g);
  k_sv2 <<<dim3(NB),     dim3(256), 0, stream>>>(E1g, E2g, W0g, W1g, entF, SV);
  k_vagg2<<<dim3(NB/16, 2), dim3(256), 0, stream>>>(SV, Hb, S1, WxF, Wxb,
                                                    W1F, W1b, W2F, W2b, out);
}

// Round 14
// 63.060 us; speedup vs baseline: 1.5229x; 1.0224x over previous
//
#include <hip/hip_runtime.h>

#define NENT 100000
#define NREL 32
#define DIM  128
#define NB   2048

typedef short s8v __attribute__((ext_vector_type(8)));
typedef float f4v __attribute__((ext_vector_type(4)));

__device__ __forceinline__ unsigned short f2bf(float x){
  unsigned u = __float_as_uint(x);
  return (unsigned short)((u + 0x7fffu + ((u>>16)&1u)) >> 16);
}
__device__ __forceinline__ float bf2f(unsigned short u){
  return __uint_as_float(((unsigned)u) << 16);
}
__device__ __forceinline__ float lo2f(unsigned p){ return __uint_as_float(p << 16); }
__device__ __forceinline__ float hi2f(unsigned p){ return __uint_as_float(p & 0xffff0000u); }
__device__ __forceinline__ float leakyf(float x){ return x > 0.f ? x : 0.2f*x; }

#define GATH_BLKS  512
#define SCALE_BLKS 25000

// ---------------- initgath: gath (raw-ent renorm) ∥ scale→entF ∥ prep — no cross-block deps
__global__ __launch_bounds__(256) void k_initgath(const int* __restrict__ eidx,
                                                  const int* __restrict__ adjE,
                                                  const int* __restrict__ adjR,
                                                  const float* __restrict__ ent,
                                                  const float* __restrict__ rel,
                                                  const float* __restrict__ A1,
                                                  const float* __restrict__ A2,
                                                  const float* __restrict__ Wxw,
                                                  const float* __restrict__ W1w,
                                                  const float* __restrict__ W2w,
                                                  unsigned short* __restrict__ entF,
                                                  float* __restrict__ Pg,
                                                  unsigned short* __restrict__ A1Lf,
                                                  unsigned short* __restrict__ A2f,
                                                  unsigned short* __restrict__ WxF,
                                                  unsigned short* __restrict__ W1F,
                                                  unsigned short* __restrict__ W2F,
                                                  int* __restrict__ E1g, int* __restrict__ E2g,
                                                  int* __restrict__ R0g, int* __restrict__ R1g,
                                                  unsigned* __restrict__ ANb,
                                                  float* __restrict__ Hb, float* __restrict__ S1,
                                                  float* __restrict__ out){
  int t = threadIdx.x;
  __shared__ float srn[2][128];
  __shared__ float red[2][2];
  if (blockIdx.x < GATH_BLKS){
    // ---- gather: wave w -> b = blk*4 + w ; barrier-free, raw-ent renorm
    int w = t>>6, l = t&63;
    int b = blockIdx.x*4 + w;
    int idx = eidx[b];
    int e1 = 0;
    if (l < 16){
      e1 = adjE[idx*16 + l];
      E1g[b*16+l] = e1;
      R0g[b*16+l] = adjR[idx*16 + l];
    }
    int esrc = __shfl(e1, l>>2);
    int4 e2 = *(const int4*)(adjE + (size_t)esrc*16 + (l&3)*4);
    int4 r1 = *(const int4*)(adjR + (size_t)esrc*16 + (l&3)*4);
    *(int4*)(E2g + (size_t)b*256 + l*4) = e2;
    *(int4*)(R1g + (size_t)b*256 + l*4) = r1;
    // batch-issue all 17 row loads, then reduce
    float2 hv = *(const float2*)(ent + (size_t)idx*128 + 2*l);
    float2 rv[16];
#pragma unroll
    for (int i=0;i<16;i++){
      int e = __shfl(e1, i);
      rv[i] = *(const float2*)(ent + (size_t)e*128 + 2*l);
    }
    float ssh = hv.x*hv.x + hv.y*hv.y;
    for (int m=1;m<64;m<<=1) ssh += __shfl_xor(ssh, m);
    float sch = fminf(1.f, 1.f/(sqrtf(ssh) + 1e-7f));
    hv.x *= sch; hv.y *= sch;
    float sx = 0.f, sy = 0.f;
#pragma unroll
    for (int i=0;i<16;i++){
      float ss = rv[i].x*rv[i].x + rv[i].y*rv[i].y;
      for (int m=1;m<64;m<<=1) ss += __shfl_xor(ss, m);
      float sc = fminf(1.f, 1.f/(sqrtf(ss) + 1e-7f));
      sx += sc*rv[i].x; sy += sc*rv[i].y;
    }
    ANb[((size_t)b*2 + 0)*64 + l] = (unsigned)f2bf(hv.x) | ((unsigned)f2bf(hv.y) << 16);
    ANb[((size_t)b*2 + 1)*64 + l] = (unsigned)f2bf(sx) | ((unsigned)f2bf(sy) << 16);
    *(float2*)(Hb + (size_t)b*128 + 2*l) = hv;
    *(float2*)(out + (size_t)b*640 + 512 + 2*l) = hv;
    float2 sv = { sx, sy };
    *(float2*)(S1 + (size_t)b*128 + 2*l) = sv;
    return;
  }
  if (blockIdx.x < GATH_BLKS + SCALE_BLKS){
    int row = (blockIdx.x - GATH_BLKS)*4 + (t>>6);
    if (row >= NENT) return;
    int l = t & 63;
    float2 v = *(const float2*)(ent + (size_t)row*128 + 2*l);
    float ss = v.x*v.x + v.y*v.y;
    for (int m=1;m<64;m<<=1) ss += __shfl_xor(ss, m);
    float sc = fminf(1.f, 1.f/(sqrtf(ss) + 1e-7f));
    int p8 = __builtin_amdgcn_cvt_pk_fp8_f32(sc*v.x, sc*v.y, 0, false);
    entF[(size_t)row*64 + l] = (unsigned short)p8;
    return;
  }
  int half = t>>7, tt = t&127;
  int blk = (blockIdx.x - GATH_BLKS - SCALE_BLKS)*2 + half;
  if (blk < 32){
    int r = blk;
    float v = rel[r*128 + tt];
    float ss = v*v;
    for (int m=1;m<64;m<<=1) ss += __shfl_xor(ss, m);
    if ((tt&63)==0) red[half][tt>>6] = ss;
    __syncthreads();
    float nrm = sqrtf(red[half][0]+red[half][1]);
    float f = fminf(1.f, 1.f/(nrm + 1e-7f));
    srn[half][tt] = v*f;
    __syncthreads();
    const float4* ar = (const float4*)(A1 + tt*256 + 128);
    float acc = 0.f;
#pragma unroll
    for (int k4=0;k4<32;k4++){
      float4 a = ar[k4];
      acc += a.x*srn[half][k4*4] + a.y*srn[half][k4*4+1]
           + a.z*srn[half][k4*4+2] + a.w*srn[half][k4*4+3];
    }
    Pg[r*128 + tt] = acc;
  } else if (blk < 64){
    int bb = blk - 32;
    int fid = bb*64 + (tt>>1);
    int hf = tt&1;
    int lane = fid & 63, kc = (fid>>6)&3, dt = fid>>8;
    int d = dt*16 + (lane&15);
    int kb = kc*32 + ((lane>>4)&3)*8 + hf*4;
#pragma unroll
    for (int i=0;i<4;i++)
      A2f[fid*8 + hf*4 + i] = f2bf(A2[d*128 + kb + i]);
  } else if (blk < 96){
    int bb = blk - 64;
    int fid = bb*64 + (tt>>1);
    int hf = tt&1;
    int lane = fid & 63, kc = (fid>>6)&3, dt = fid>>8;
    int d = dt*16 + (lane&15);
    int kb = kc*32 + ((lane>>4)&3)*8 + hf*4;
#pragma unroll
    for (int i=0;i<4;i++)
      A1Lf[fid*8 + hf*4 + i] = f2bf(A1[d*256 + kb + i]);
  } else if (blk < 160){
    int fid = (blk-96)*128 + tt;
    int l = fid&63, kc = (fid>>6)&3, nt = (fid>>8)&15, iter = (fid>>12)&1;
    int n = nt*16 + (l&15);
    int k = kc*32 + ((l>>4)&3)*8;
    const float* src = Wxw + ((size_t)((iter*2 + (n>>7))*128 + (n&127)))*128 + k;
#pragma unroll
    for (int j=0;j<8;j++) WxF[(size_t)fid*8 + j] = f2bf(src[j]);
  } else if (blk < 224){
    int fid = (blk-160)*128 + tt;
    int l = fid&63, kc = (fid>>6)&7, nt = (fid>>9)&15;
    int n = nt*16 + (l&15);
    int k = kc*32 + ((l>>4)&3)*8;
#pragma unroll
    for (int j=0;j<8;j++) W1F[(size_t)fid*8 + j] = f2bf(W1w[(size_t)n*256 + k + j]);
  } else {
    int fid = (blk-224)*128 + tt;
    int l = fid&63, kc = (fid>>6)&7, nt = (fid>>9)&15;
    int n = nt*16 + (l&15);
    int k = kc*32 + ((l>>4)&3)*8;
#pragma unroll
    for (int j=0;j<8;j++) W2F[(size_t)fid*8 + j] = f2bf(W2w[(size_t)n*256 + k + j]);
  }
}

// ---------------- batched scores: 4 b/block, 8 waves, A2f LDS-staged
__global__ __launch_bounds__(512) void k_score2(const unsigned* __restrict__ ANb,
                                                const unsigned short* __restrict__ A1Lf,
                                                const float* __restrict__ Pg,
                                                const unsigned short* __restrict__ A2f,
                                                const float* __restrict__ A3,
                                                const int* __restrict__ R0g,
                                                const int* __restrict__ R1g,
                                                float* __restrict__ W0g,
                                                float* __restrict__ W1g){
  int blk = blockIdx.x;              // 4 b per block
  int t = threadIdx.x, l = t&63, w = t>>6;   // 8 waves
  __shared__ __align__(16) unsigned short sA2f[2048*8];  // 32 KB
  __shared__ __align__(16) unsigned sAN[16*64];          // 8 anchors (rows 8..15 zero), swizzled
  __shared__ float sC[8][132];
  __shared__ float sSC[4][64];

  { // stage A2f (32 KB, 4 uint4/thread) + anchors
    const uint4* src = (const uint4*)A2f;
    uint4* dst = (uint4*)sA2f;
#pragma unroll
    for (int i=0;i<4;i++) dst[t + i*512] = src[t + i*512];
    if (t < 256){
      int row = t>>4, seg = t&15;
      uint4 v = {0u,0u,0u,0u};
      if (row < 8) v = *(const uint4*)(ANb + ((size_t)blk*8 + row)*64 + seg*4);
      *(uint4*)((char*)sAN + ((row*256 + seg*16) ^ ((row&7)<<4))) = v;
    }
  }
  __syncthreads();

  int cl = l&15, kg = l>>4;
  { // G1: c = A1L @ anchors ; wave w -> dt = w
    s8v bf[4];
#pragma unroll
    for (int kc=0;kc<4;kc++)
      bf[kc] = *(const s8v*)((const char*)sAN + ((cl*256 + (kc*32+kg*8)*2) ^ ((cl&7)<<4)));
    int dt = w;
    f4v acc = {0.f,0.f,0.f,0.f};
#pragma unroll
    for (int kc=0;kc<4;kc++){
      s8v af = *(const s8v*)(A1Lf + ((size_t)((dt*4+kc)*64 + l))*8);
      acc = __builtin_amdgcn_mfma_f32_16x16x32_bf16(af, bf[kc], acc, 0, 0, 0);
    }
    if (cl < 8){
#pragma unroll
      for (int r=0;r<4;r++) sC[cl][dt*16 + kg*4 + r] = acc[r];
    }
  }
  __syncthreads();

  { // G2: wave w -> anchor ci = w ; cc splits relations (rr = cc*16+cl)
    s8v bfr0[4], bfr1[4];
#pragma unroll
    for (int cc=0; cc<2; cc++){
      int ci = w;
      int rr = cc*16 + cl;
      s8v* bfr = cc ? bfr1 : bfr0;
#pragma unroll
      for (int kc=0;kc<4;kc++){
        int k0 = kc*32 + kg*8;
        float4 pa = *(const float4*)(Pg + rr*128 + k0);
        float4 pb = *(const float4*)(Pg + rr*128 + k0 + 4);
        bfr[kc][0] = (short)f2bf(fmaxf(sC[ci][k0+0]+pa.x, 0.f));
        bfr[kc][1] = (short)f2bf(fmaxf(sC[ci][k0+1]+pa.y, 0.f));
        bfr[kc][2] = (short)f2bf(fmaxf(sC[ci][k0+2]+pa.z, 0.f));
        bfr[kc][3] = (short)f2bf(fmaxf(sC[ci][k0+3]+pa.w, 0.f));
        bfr[kc][4] = (short)f2bf(fmaxf(sC[ci][k0+4]+pb.x, 0.f));
        bfr[kc][5] = (short)f2bf(fmaxf(sC[ci][k0+5]+pb.y, 0.f));
        bfr[kc][6] = (short)f2bf(fmaxf(sC[ci][k0+6]+pb.z, 0.f));
        bfr[kc][7] = (short)f2bf(fmaxf(sC[ci][k0+7]+pb.w, 0.f));
      }
    }
    float sacc0 = 0.f, sacc1 = 0.f;
#pragma unroll
    for (int dt=0; dt<8; dt++){
      f4v a40 = {0.f,0.f,0.f,0.f};
      f4v a41 = {0.f,0.f,0.f,0.f};
#pragma unroll
      for (int kc=0;kc<4;kc++){
        s8v af = *(const s8v*)(sA2f + ((dt*4+kc)*64 + l)*8);
        a40 = __builtin_amdgcn_mfma_f32_16x16x32_bf16(af, bfr0[kc], a40, 0, 0, 0);
        a41 = __builtin_amdgcn_mfma_f32_16x16x32_bf16(af, bfr1[kc], a41, 0, 0, 0);
      }
      float4 a3v = *(const float4*)(A3 + dt*16 + kg*4);
      sacc0 += fmaxf(a40[0],0.f)*a3v.x + fmaxf(a40[1],0.f)*a3v.y
             + fmaxf(a40[2],0.f)*a3v.z + fmaxf(a40[3],0.f)*a3v.w;
      sacc1 += fmaxf(a41[0],0.f)*a3v.x + fmaxf(a41[1],0.f)*a3v.y
             + fmaxf(a41[2],0.f)*a3v.z + fmaxf(a41[3],0.f)*a3v.w;
    }
    sacc0 += __shfl_xor(sacc0, 16); sacc0 += __shfl_xor(sacc0, 32);
    sacc1 += __shfl_xor(sacc1, 16); sacc1 += __shfl_xor(sacc1, 32);
    if (l < 16){
      int c0 = (w*2+0)*16 + l;
      int c1 = (w*2+1)*16 + l;
      sSC[c0>>6][c0&63] = 1.f/(1.f + __expf(-sacc0));
      sSC[c1>>6][c1&63] = 1.f/(1.f + __expf(-sacc1));
    }
  }
  __syncthreads();

  if (w < 4){ // softmax: wave w -> b = blk*4 + w
    int b = blk*4 + w;
    int4 ra = *(const int4*)(R1g + (size_t)b*256 + l*4);
    float e0 = __expf(sSC[w][32 + ra.x]);
    float e1 = __expf(sSC[w][32 + ra.y]);
    float e2 = __expf(sSC[w][32 + ra.z]);
    float e3 = __expf(sSC[w][32 + ra.w]);
    float s = e0+e1+e2+e3;
    for (int m=1;m<64;m<<=1) s += __shfl_xor(s, m);
    float inv = 1.f/s;
    float4 o = { e0*inv, e1*inv, e2*inv, e3*inv };
    *(float4*)(W1g + (size_t)b*256 + l*4) = o;
    if (l < 16){
      float ee = __expf(sSC[w][R0g[b*16 + l]]);
      float s0 = ee;
      for (int m=1;m<16;m<<=1) s0 += __shfl_xor(s0, m);
      W0g[b*16 + l] = ee/s0;
    }
  }
}

// ---------------- weighted gathers v3: 8 waves/b, 2 rows/load, 16-deep MLP, fp8
__global__ __launch_bounds__(512) void k_sv3(const int* __restrict__ E1g,
                                             const int* __restrict__ E2g,
                                             const float* __restrict__ W0g,
                                             const float* __restrict__ W1g,
                                             const unsigned short* __restrict__ entF,
                                             float* __restrict__ SV){
  int b = blockIdx.x, t = threadIdx.x, l = t&63, w = t>>6;
  __shared__ int sE1[16];
  __shared__ float sW0[16];
  __shared__ int sE2[256];
  __shared__ float sW1[256];
  __shared__ float sPart[8][128];
  if (t < 16){ sE1[t] = E1g[b*16+t]; sW0[t] = W0g[b*16+t]; }
  if (t >= 256){ int i = t-256; sE2[i] = E2g[b*256+i]; sW1[i] = W1g[b*256+i]; }
  __syncthreads();

  const unsigned* eF = (const unsigned*)entF;   // 32 uints (=128 dims) per row
  int half = l>>5, j = l&31;

  // hop-2: wave w rows [w*32, w*32+32), 2 rows per iter, 16 independent loads
  f4v a1 = {0.f,0.f,0.f,0.f};
#pragma unroll
  for (int i=0;i<16;i++){
    int row = w*32 + i*2 + half;
    float f = sW1[row];
    unsigned q = eF[(size_t)sE2[row]*32 + j];
    a1[0] += f*__builtin_amdgcn_cvt_f32_fp8((int)q, 0);
    a1[1] += f*__builtin_amdgcn_cvt_f32_fp8((int)q, 1);
    a1[2] += f*__builtin_amdgcn_cvt_f32_fp8((int)q, 2);
    a1[3] += f*__builtin_amdgcn_cvt_f32_fp8((int)q, 3);
  }
  // hop-1: wave w rows w*2 + half (16 rows over 8 waves)
  f4v a0;
  {
    int row = w*2 + half;
    float f = sW0[row];
    unsigned q = eF[(size_t)sE1[row]*32 + j];
    a0[0] = f*__builtin_amdgcn_cvt_f32_fp8((int)q, 0);
    a0[1] = f*__builtin_amdgcn_cvt_f32_fp8((int)q, 1);
    a0[2] = f*__builtin_amdgcn_cvt_f32_fp8((int)q, 2);
    a0[3] = f*__builtin_amdgcn_cvt_f32_fp8((int)q, 3);
  }
#pragma unroll
  for (int r=0;r<4;r++){
    a1[r] += __shfl_xor(a1[r], 32);
    a0[r] += __shfl_xor(a0[r], 32);
  }
  if (half == 0) *(float4*)&sPart[w][j*4] = *(float4*)&a1;
  __syncthreads();
  if (t < 128){
    float s = 0.f;
#pragma unroll
    for (int ww=0;ww<8;ww++) s += sPart[ww][t];
    SV[((size_t)b*2 + 1)*128 + t] = s;
  }
  __syncthreads();
  if (half == 0) *(float4*)&sPart[w][j*4] = *(float4*)&a0;
  __syncthreads();
  if (t < 128){
    float s = 0.f;
#pragma unroll
    for (int ww=0;ww<8;ww++) s += sPart[ww][t];
    SV[((size_t)b*2 + 0)*128 + t] = s;
  }
}

// ---------------- MFMA vagg: 16-row tiles, grid (128, 2) — all CUs busy
__global__ __launch_bounds__(256) void k_vagg2(const float* __restrict__ SV,
                                               const float* __restrict__ Hb,
                                               const float* __restrict__ S1,
                                               const unsigned short* __restrict__ WxF,
                                               const float* __restrict__ Wxb,
                                               const unsigned short* __restrict__ W1F,
                                               const float* __restrict__ W1b,
                                               const unsigned short* __restrict__ W2F,
                                               const float* __restrict__ W2b,
                                               float* __restrict__ out){
  int b0 = blockIdx.x * 16;
  int iter = blockIdx.y;
  int t = threadIdx.x, l = t&63, w = t>>6;
  __shared__ __align__(16) unsigned short sSV[16*128];
  __shared__ __align__(16) unsigned short sA [16*128];
  __shared__ __align__(16) unsigned short sV [16*256];
  char* sSVb = (char*)sSV; char* sAb = (char*)sA; char* sVb = (char*)sV;

  const float* anc = iter ? S1 : Hb;
  {
    int row = t>>4, c0 = (t&15)*8;
    const float* ps = SV + ((size_t)(b0+row)*2 + iter)*128 + c0;
    const float* pa = anc + (size_t)(b0+row)*128 + c0;
    int xo = (row&7)<<4;
#pragma unroll
    for (int c2=0;c2<4;c2++){
      float2 sv2 = *(const float2*)(ps + c2*2);
      float2 an2 = *(const float2*)(pa + c2*2);
      unsigned pv  = (unsigned)f2bf(sv2.x) | ((unsigned)f2bf(sv2.y)<<16);
      unsigned pan = (unsigned)f2bf(an2.x) | ((unsigned)f2bf(an2.y)<<16);
      int byte = (row*256 + c0*2 + c2*4) ^ xo;
      *(unsigned*)(sSVb + byte) = pv;
      *(unsigned*)(sAb  + byte) = pan;
    }
  }
  __syncthreads();

  int kl = l&15, kg = l>>4;
  { // G1: wave w -> col-tiles ntg = w*4..w*4+3 (rows 0..15)
    int rowg = kl;
    int xo = (rowg&7)<<4;
    s8v af[4];
#pragma unroll
    for (int kc=0;kc<4;kc++)
      af[kc] = *(const s8v*)(sSVb + ((rowg*256 + kc*64 + kg*16) ^ xo));
#pragma unroll
    for (int nt4=0;nt4<4;nt4++){
      int ntg = w*4 + nt4;
      int n = ntg*16 + kl;
      float bias = Wxb[iter*256 + n];
      f4v acc = {bias,bias,bias,bias};
#pragma unroll
      for (int kc=0;kc<4;kc++){
        s8v bf = *(const s8v*)(WxF + ((size_t)(((iter*16 + ntg)*4 + kc)*64 + l))*8);
        acc = __builtin_amdgcn_mfma_f32_16x16x32_bf16(af[kc], bf, acc, 0, 0, 0);
      }
#pragma unroll
      for (int r=0;r<4;r++){
        int rowl = kg*4 + r;
        int byte = (rowl*512 + n*2) ^ ((rowl&7)<<4);
        *(unsigned short*)(sVb + byte) = f2bf(leakyf(acc[r]));
      }
    }
  }
  __syncthreads();
  {
    int rowl = kl;
    int xo = (rowl&7)<<4;
    s8v x1f[8], x2f[8];
#pragma unroll
    for (int kc=0;kc<8;kc++){
      int k0 = kc*32 + kg*8;
      s8v vv = *(const s8v*)(sVb + ((rowl*512 + k0*2) ^ xo));
      s8v aa = *(const s8v*)(sAb + ((rowl*256 + (k0&127)*2) ^ xo));
#pragma unroll
      for (int j=0;j<8;j++){
        float vf = bf2f((unsigned short)vv[j]);
        float av = bf2f((unsigned short)aa[j]);
        x1f[kc][j] = (short)f2bf(av + vf);
        x2f[kc][j] = (short)f2bf(av * vf);
      }
    }
    int obase = iter ? 0 : 256;
#pragma unroll
    for (int nt4=0;nt4<4;nt4++){
      int ntg = w*4 + nt4;
      int n = ntg*16 + kl;
      float bb1 = W1b[n], bb2 = W2b[n];
      f4v a1 = {bb1,bb1,bb1,bb1};
      f4v a2 = {bb2,bb2,bb2,bb2};
#pragma unroll
      for (int kc=0;kc<8;kc++){
        s8v wf1 = *(const s8v*)(W1F + ((size_t)((ntg*8 + kc)*64 + l))*8);
        a1 = __builtin_amdgcn_mfma_f32_16x16x32_bf16(x1f[kc], wf1, a1, 0, 0, 0);
      }
#pragma unroll
      for (int kc=0;kc<8;kc++){
        s8v wf2 = *(const s8v*)(W2F + ((size_t)((ntg*8 + kc)*64 + l))*8);
        a2 = __builtin_amdgcn_mfma_f32_16x16x32_bf16(x2f[kc], wf2, a2, 0, 0, 0);
      }
#pragma unroll
      for (int r=0;r<4;r++){
        int row = kg*4 + r;
        out[(size_t)(b0+row)*640 + obase + n] = leakyf(a1[r]) + leakyf(a2[r]);
      }
    }
  }
}

extern "C" void kernel_launch(void* const* d_in, const int* in_sizes, int n_in,
                              void* d_out, int out_size, void* d_ws, size_t ws_size,
                              hipStream_t stream) {
  const int*   eidx = (const int*)d_in[0];
  const int*   adjE = (const int*)d_in[1];
  const int*   adjR = (const int*)d_in[2];
  const float* ent  = (const float*)d_in[3];
  const float* rel  = (const float*)d_in[4];
  const float* A1   = (const float*)d_in[5];
  const float* A2   = (const float*)d_in[6];
  const float* A3   = (const float*)d_in[7];
  const float* Wxw  = (const float*)d_in[8];
  const float* Wxb  = (const float*)d_in[9];
  const float* W1w  = (const float*)d_in[10];
  const float* W1b  = (const float*)d_in[11];
  const float* W2w  = (const float*)d_in[12];
  const float* W2b  = (const float*)d_in[13];
  float* out = (float*)d_out;

  char* wsb = (char*)d_ws;
  size_t off = 0;
  auto alloc = [&](size_t bytes)->char*{
    char* p = wsb + off; off += (bytes + 255) & ~(size_t)255; return p;
  };
  float* Pg   = (float*)alloc(NREL*DIM*4);
  unsigned short* A1Lf = (unsigned short*)alloc(2048*8*2);
  unsigned short* A2f  = (unsigned short*)alloc(2048*8*2);
  unsigned short* WxF = (unsigned short*)alloc((size_t)8192*8*2);
  unsigned short* W1F = (unsigned short*)alloc((size_t)8192*8*2);
  unsigned short* W2F = (unsigned short*)alloc((size_t)8192*8*2);
  unsigned short* entF = (unsigned short*)alloc((size_t)NENT*64*2);
  unsigned* ANb  = (unsigned*)alloc((size_t)NB*2*64*4);
  float* Hb = (float*)alloc((size_t)NB*DIM*4);
  float* S1 = (float*)alloc((size_t)NB*DIM*4);
  float* SV = (float*)alloc((size_t)NB*2*DIM*4);
  int* E1g = (int*)alloc((size_t)NB*16*4);
  int* E2g = (int*)alloc((size_t)NB*256*4);
  int* R0g = (int*)alloc((size_t)NB*16*4);
  int* R1g = (int*)alloc((size_t)NB*256*4);
  float* W0g = (float*)alloc((size_t)NB*16*4);
  float* W1g = (float*)alloc((size_t)NB*256*4);

  k_initgath<<<dim3(GATH_BLKS + SCALE_BLKS + 144), dim3(256), 0, stream>>>(
      eidx, adjE, adjR, ent, rel, A1, A2, Wxw, W1w, W2w,
      entF, Pg, A1Lf, A2f, WxF, W1F, W2F,
      E1g, E2g, R0g, R1g, ANb, Hb, S1, out);
  k_score2<<<dim3(NB/4), dim3(512), 0, stream>>>(ANb, A1Lf, Pg, A2f, A3,
                                                 R0g, R1g, W0g, W1g);
  k_sv3 <<<dim3(NB),     dim3(512), 0, stream>>>(E1g, E2g, W0g, W1g, entF, SV);
  k_vagg2<<<dim3(NB/16, 2), dim3(256), 0, stream>>>(SV, Hb, S1, WxF, Wxb,
                                                    W1F, W1b, W2F, W2b, out);
}